// Round 6
// baseline (762.590 us; speedup 1.0000x reference)
//
#include <hip/hip_runtime.h>

#define HW 65536

typedef __bf16 bf16x8 __attribute__((ext_vector_type(8)));
typedef float f32x16 __attribute__((ext_vector_type(16)));

__device__ inline unsigned short f2bf(float x) {
    union { float f; unsigned u; } v; v.f = x;
    unsigned r = v.u + 0x7FFF + ((v.u >> 16) & 1);   // RNE
    return (unsigned short)(r >> 16);
}
__device__ inline float bfhi2f(unsigned u) {        // high 16 bits as f32
    union { unsigned u; float f; } v; v.u = u & 0xffff0000u; return v.f;
}
__device__ inline float bflo2f(unsigned u) {        // low 16 bits as f32
    union { unsigned u; float f; } v; v.u = u << 16; return v.f;
}

union FragU { uint4 u; bf16x8 v; };
__device__ inline bf16x8 ld_frag(const uint4* p) { FragU t; t.u = *p; return t.v; }

// ---------------------------------------------------------------------------
// Weight pre-transform (+ grid-barrier state zeroing).
// y<6  : 3x3 conv weights -> fragment-linear [(tap*8+igg)*64+oc]*8+j
// y==6 : kg_w5 combine layout (consumed by jbfm stage)
// y==7 : tensor 1x1 weights -> [kg*64+oc]*8+j
// ---------------------------------------------------------------------------
__global__ __launch_bounds__(256) void k_wprep(
    const float* __restrict__ w0, const float* __restrict__ w1,
    const float* __restrict__ w2, const float* __restrict__ w3,
    const float* __restrict__ w4, const float* __restrict__ w5,
    const float* __restrict__ w5c, const float* __restrict__ tw,
    unsigned short* __restrict__ wT, unsigned long long* __restrict__ bar)
{
    int y = blockIdx.y;
    unsigned short* o = wT + (size_t)y * 36864;
    if (y == 7 && blockIdx.x == 0 && threadIdx.x == 0) *bar = 0ull;
    if (y < 6) {
        const float* ws_[6] = {w0, w1, w2, w3, w4, w5};
        const float* w = ws_[y];
        for (int e = blockIdx.x * 256 + threadIdx.x; e < 36864; e += gridDim.x * 256) {
            int tap = e >> 12, oc = (e >> 6) & 63, ic = e & 63;
            int igg = ic >> 3, j = ic & 7;
            int dst = ((tap * 8 + igg) * 64 + oc) * 8 + j;
            o[dst] = f2bf(w[(oc * 64 + ic) * 9 + tap]);
        }
    } else if (y == 6) {
        for (int e = blockIdx.x * 256 + threadIdx.x; e < 36864; e += gridDim.x * 256)
            o[e] = f2bf(w5c[e]);
    } else {
        for (int e = blockIdx.x * 256 + threadIdx.x; e < 8192; e += gridDim.x * 256) {
            int oc = e >> 7, ic = e & 127;
            int kg = ic >> 3, j = ic & 7;
            o[((kg * 64 + oc) << 3) + j] = f2bf(tw[e]);
        }
    }
}

// ---------------------------------------------------------------------------
// k_tr: NCHW fp32 -> NHWC bf16 for img and guidance (64-px x 64-ch tiles).
// ---------------------------------------------------------------------------
__global__ __launch_bounds__(256) void k_tr(
    const float* __restrict__ img, const float* __restrict__ gd,
    unsigned short* __restrict__ imgT, unsigned short* __restrict__ gdT)
{
    __shared__ float sT[64 * 66];   // [ic][66] fp32 (stride 66 -> spread reads)
    int tid = threadIdx.x;
    int z = blockIdx.y;             // tensor*2 + b
    int b = z & 1;
    const float* src = (z >> 1) ? gd : img;
    unsigned short* dst = (z >> 1) ? gdT : imgT;
    int px0 = blockIdx.x * 64;
    size_t sbase = (size_t)b * 64 * HW + px0;

#pragma unroll
    for (int i = 0; i < 4; ++i) {
        int e = i * 256 + tid;                 // [0,1024)
        int ic = e >> 4, seg = e & 15;
        float4 v = *(const float4*)(src + sbase + (size_t)ic * HW + seg * 4);
        float* p = &sT[ic * 66 + seg * 4];
        ((float2*)p)[0] = make_float2(v.x, v.y);
        ((float2*)p)[1] = make_float2(v.z, v.w);
    }
    __syncthreads();

    size_t dbase = (size_t)b * HW * 64 + (size_t)px0 * 64;
#pragma unroll
    for (int k = 0; k < 2; ++k) {
        int idx = k * 256 + tid;               // [0,512)
        int px = idx >> 3, u = idx & 7;
        union { uint4 q; unsigned short h[8]; } o;
#pragma unroll
        for (int j = 0; j < 8; ++j)
            o.h[j] = f2bf(sT[(u * 8 + j) * 66 + px]);
        *(uint4*)(dst + dbase + (size_t)px * 64 + u * 8) = o.q;
    }
}

// ---------------------------------------------------------------------------
// Grid barrier: generation-based, 64-bit {gen:32, cnt:32}. Release-only L2
// writeback when wb (cross-XCD halo hand-off); NO acquire invalidate (buffer
// discipline guarantees no stale-clean reads), preserving own-XCD L2 reuse.
// ---------------------------------------------------------------------------
__device__ __forceinline__ void gbar(unsigned long long* bar, bool wb) {
    __syncthreads();                 // drains all waves' vmem (compiler emits waitcnt)
    if (threadIdx.x == 0) {
        if (wb) __builtin_amdgcn_fence(__ATOMIC_RELEASE, "agent");  // wb dirty L2
        unsigned long long v = __hip_atomic_fetch_add(bar, 1ull,
            __ATOMIC_RELAXED, __HIP_MEMORY_SCOPE_AGENT);
        unsigned g = (unsigned)(v >> 32);
        unsigned c = (unsigned)v;
        if (c == 511u) {
            __hip_atomic_store(bar, (unsigned long long)(g + 1u) << 32,
                __ATOMIC_RELAXED, __HIP_MEMORY_SCOPE_AGENT);
        } else {
            while ((unsigned)(__hip_atomic_load(bar, __ATOMIC_RELAXED,
                       __HIP_MEMORY_SCOPE_AGENT) >> 32) == g)
                __builtin_amdgcn_s_sleep(8);
        }
    }
    __syncthreads();
}

// ---------------------------------------------------------------------------
// Stage: fusem — 1x1 (2C->C) + PReLU, one 16x8 tile.
// ---------------------------------------------------------------------------
__device__ __forceinline__ void st_fusem(char* smem, int tid, int t,
    const unsigned short* imgT, const unsigned short* gdT, const uint4* wg,
    const float* bias, const float* a, unsigned short* out)
{
    uint4* sX = (uint4*)smem;                     // 1152 uint4
    float* sB = (float*)(smem + 18432);
    unsigned short* sT16 = (unsigned short*)smem;

    int wv = tid >> 6, lane = tid & 63;
    int half = lane >> 5, l31 = lane & 31;
    int b = t >> 9, rem = t & 511;
    int y0 = (rem >> 4) * 8, x0 = (rem & 15) * 16;
    size_t zbase = (size_t)b * HW * 64;

    __syncthreads();
    if (tid < 64) sB[tid] = bias[tid];

    f32x16 acc[2];
#pragma unroll
    for (int i = 0; i < 2; ++i)
#pragma unroll
        for (int r = 0; r < 16; ++r) acc[i][r] = 0.f;

    auto loadX = [&](const unsigned short* src, uint4* rx) {
#pragma unroll
        for (int i = 0; i < 4; ++i) {
            int e = i * 256 + tid;
            int px = e >> 3, ig = e & 7;
            int gy = y0 + (px >> 4), gx = x0 + (px & 15);
            rx[i] = *(const uint4*)(src + zbase + ((size_t)(gy * 256 + gx)) * 64 + ig * 8);
        }
    };
    auto writeX = [&](const uint4* rx) {
#pragma unroll
        for (int i = 0; i < 4; ++i) {
            int e = i * 256 + tid;
            sX[(e >> 3) * 9 + (e & 7)] = rx[i];
        }
    };
    auto compute = [&](int h) {
#pragma unroll
        for (int c = 0; c < 4; ++c) {
            int ig = c * 2 + half;
            int kg = h * 8 + ig;
            bf16x8 a0 = ld_frag(&wg[kg * 64 + l31]);
            bf16x8 a1 = ld_frag(&wg[kg * 64 + 32 + l31]);
            int p0 = wv * 32 + l31;
            bf16x8 b0 = ld_frag(&sX[p0 * 9 + ig]);
            acc[0] = __builtin_amdgcn_mfma_f32_32x32x16_bf16(a0, b0, acc[0], 0, 0, 0);
            acc[1] = __builtin_amdgcn_mfma_f32_32x32x16_bf16(a1, b0, acc[1], 0, 0, 0);
        }
    };

    uint4 rx[4], ry[4];
    loadX(imgT, rx);
    writeX(rx);
    loadX(gdT, ry);        // prefetch h1
    __syncthreads();
    compute(0);
    __syncthreads();
    writeX(ry);
    __syncthreads();
    compute(1);

    float slope = a[0];
    __syncthreads();
    {
        int px = wv * 32 + l31;
#pragma unroll
        for (int ot = 0; ot < 2; ++ot)
#pragma unroll
            for (int q2 = 0; q2 < 4; ++q2) {
                unsigned short hw[4];
#pragma unroll
                for (int j = 0; j < 4; ++j) {
                    int r = (q2 << 2) | j;
                    int oc = ot * 32 + j + 8 * q2 + 4 * half;
                    float v = acc[ot][r] + sB[oc];
                    v = (v >= 0.f) ? v : slope * v;
                    hw[j] = f2bf(v);
                }
                int up = (ot * 4 + q2) ^ (px & 7);
                uint2* p = (uint2*)&sT16[px * 64 + up * 8 + half * 4];
                *p = make_uint2((unsigned)hw[0] | ((unsigned)hw[1] << 16),
                                (unsigned)hw[2] | ((unsigned)hw[3] << 16));
            }
    }
    __syncthreads();
#pragma unroll
    for (int k = 0; k < 4; ++k) {
        int idx = k * 256 + tid;
        int row = idx >> 7, rem2 = idx & 127;
        int col = rem2 >> 3, u = rem2 & 7;
        int px = row * 16 + col;
        uint4 v = *(uint4*)&sT16[px * 64 + (u ^ (px & 7)) * 8];
        *(uint4*)(out + zbase + ((size_t)((y0 + row) * 256 + x0 + col)) * 64 + u * 8) = v;
    }
}

// ---------------------------------------------------------------------------
// Stage: fused double 3x3 conv, one 16x8 tile (round-5 oc-split structure).
// ---------------------------------------------------------------------------
#define XU 5

template<int MODE>
__device__ __forceinline__ void st_conv2x(char* smem, int tid, int t,
    const unsigned short* in, const uint4* wg1, const uint4* wg2,
    const float* b1, const float* b2, const float* a,
    const float* res, void* outv)
{
    uint4* sIn0 = (uint4*)smem;                    // 1200 uint4
    uint4* sIn1 = (uint4*)(smem + 19200);
    float* sB = (float*)(smem + 38400);

    int wv = tid >> 6, lane = tid & 63;
    int half = lane >> 5, l31 = lane & 31;
    int w2 = wv >> 1, g = wv & 1;
    int b = t >> 9, rem = t & 511;
    int y0 = (rem >> 4) * 8, x0 = (rem & 15) * 16;
    const size_t zbase = (size_t)b * HW * 64;

    __syncthreads();
    if (tid < 64) sB[tid] = b1[tid];
    else if (tid < 128) sB[tid] = b2[tid - 64];

    auto loadIn = [&](int h, uint4* rx) {
#pragma unroll
        for (int i = 0; i < 4; ++i) {
            int e = i * 256 + tid;
            int cell = e >> 2, ig = e & 3;
            int r = cell / 20, c2 = cell - r * 20;
            int gy = y0 - 2 + r, gx = x0 - 2 + c2;
            rx[i] = make_uint4(0, 0, 0, 0);
            bool act = (i < 3) || (e < 960);
            if (act && gy >= 0 && gy < 256 && gx >= 0 && gx < 256)
                rx[i] = *(const uint4*)(in + zbase + ((size_t)(gy * 256 + gx)) * 64 + h * 32 + ig * 8);
        }
    };
    auto writeIn = [&](uint4* s, const uint4* rx) {
#pragma unroll
        for (int i = 0; i < 4; ++i) {
            int e = i * 256 + tid;
            if (i < 3 || e < 960) s[(e >> 2) * XU + (e & 3)] = rx[i];
        }
    };

    int cellv[3], ibv[3];
#pragma unroll
    for (int s = 0; s < 3; ++s) {
        int c = g * 96 + s * 32 + l31;
        cellv[s] = c;
        int cc = c < 180 ? c : 179;
        ibv[s] = (cc / 18) * 20 + (cc % 18);
    }

    f32x16 acc1[3];
#pragma unroll
    for (int s = 0; s < 3; ++s)
#pragma unroll
        for (int r = 0; r < 16; ++r) acc1[s][r] = 0.f;

    auto conv1_h = [&](int h, const uint4* sInp) {
#pragma unroll
        for (int dy = 0; dy < 3; ++dy) {
#pragma unroll
            for (int dx = 0; dx < 3; ++dx) {
                int tap = dy * 3 + dx;
                int doff = dy * 20 + dx;
#pragma unroll
                for (int c = 0; c < 2; ++c) {
                    int ig = c * 2 + half;
                    bf16x8 af = ld_frag(&wg1[(tap * 8 + h * 4 + ig) * 64 + w2 * 32 + l31]);
#pragma unroll
                    for (int s = 0; s < 3; ++s) {
                        bf16x8 bb = ld_frag(&sInp[(ibv[s] + doff) * XU + ig]);
                        acc1[s] = __builtin_amdgcn_mfma_f32_32x32x16_bf16(af, bb, acc1[s], 0, 0, 0);
                    }
                }
            }
        }
    };

    uint4 rx[4];
    loadIn(0, rx);
    writeIn(sIn0, rx);
    uint4 ry[4];
    loadIn(1, ry);
    __syncthreads();
    conv1_h(0, sIn0);
    writeIn(sIn1, ry);
    __syncthreads();
    conv1_h(1, sIn1);

    float s1 = a[0];
    __syncthreads();
    unsigned short* sC16 = (unsigned short*)smem;
#pragma unroll
    for (int s = 0; s < 3; ++s) {
        int cell = cellv[s];
        if (cell < 180) {
            int orow = cell / 18, ocol = cell - orow * 18;
            int gy = y0 - 1 + orow, gx = x0 - 1 + ocol;
            bool inb = (gy >= 0 && gy < 256 && gx >= 0 && gx < 256);
#pragma unroll
            for (int q2 = 0; q2 < 4; ++q2) {
                unsigned short hw[4];
#pragma unroll
                for (int j = 0; j < 4; ++j) {
                    int r = (q2 << 2) | j;
                    int oc = w2 * 32 + j + 8 * q2 + 4 * half;
                    float v = acc1[s][r] + sB[oc];
                    v = (v >= 0.f) ? v : s1 * v;
                    if (!inb) v = 0.f;
                    hw[j] = f2bf(v);
                }
                int up = (w2 * 4 + q2) ^ (cell & 7);
                *(uint2*)&sC16[cell * 64 + up * 8 + half * 4] =
                    make_uint2((unsigned)hw[0] | ((unsigned)hw[1] << 16),
                               (unsigned)hw[2] | ((unsigned)hw[3] << 16));
            }
        }
    }
    __syncthreads();

    f32x16 acc2[2];
#pragma unroll
    for (int s = 0; s < 2; ++s)
#pragma unroll
        for (int r = 0; r < 16; ++r) acc2[s][r] = 0.f;

    int rowS[2], colS[2];
#pragma unroll
    for (int s = 0; s < 2; ++s) {
        int px = g * 64 + s * 32 + l31;
        rowS[s] = px >> 4; colS[s] = px & 15;
    }
    {
        const uint4* sC4 = (const uint4*)smem;
#pragma unroll
        for (int dy = 0; dy < 3; ++dy) {
#pragma unroll
            for (int dx = 0; dx < 3; ++dx) {
                int tap = dy * 3 + dx;
#pragma unroll
                for (int c = 0; c < 4; ++c) {
                    int ig = c * 2 + half;
                    bf16x8 af = ld_frag(&wg2[(tap * 8 + ig) * 64 + w2 * 32 + l31]);
#pragma unroll
                    for (int s = 0; s < 2; ++s) {
                        int cl = (rowS[s] + dy) * 18 + colS[s] + dx;
                        bf16x8 bb = ld_frag(&sC4[cl * 8 + (ig ^ (cl & 7))]);
                        acc2[s] = __builtin_amdgcn_mfma_f32_32x32x16_bf16(af, bb, acc2[s], 0, 0, 0);
                    }
                }
            }
        }
    }

    if (MODE == 0) {
        __syncthreads();
        unsigned short* sT16 = (unsigned short*)smem;
#pragma unroll
        for (int s = 0; s < 2; ++s) {
            int px = g * 64 + s * 32 + l31;
#pragma unroll
            for (int q2 = 0; q2 < 4; ++q2) {
                unsigned short hw[4];
#pragma unroll
                for (int j = 0; j < 4; ++j) {
                    int r = (q2 << 2) | j;
                    int oc = w2 * 32 + j + 8 * q2 + 4 * half;
                    float v = acc2[s][r] + sB[64 + oc];
                    v = (v >= 0.f) ? v : s1 * v;
                    hw[j] = f2bf(v);
                }
                int up = (w2 * 4 + q2) ^ (px & 7);
                uint2* p = (uint2*)&sT16[px * 64 + up * 8 + half * 4];
                *p = make_uint2((unsigned)hw[0] | ((unsigned)hw[1] << 16),
                                (unsigned)hw[2] | ((unsigned)hw[3] << 16));
            }
        }
        __syncthreads();
        unsigned short* outT = (unsigned short*)outv;
#pragma unroll
        for (int k = 0; k < 4; ++k) {
            int idx = k * 256 + tid;
            int row = idx >> 7, rem2 = idx & 127;
            int col = rem2 >> 3, u = rem2 & 7;
            int px = row * 16 + col;
            uint4 v = *(uint4*)&sT16[px * 64 + (u ^ (px & 7)) * 8];
            *(uint4*)(outT + zbase + ((size_t)((y0 + row) * 256 + x0 + col)) * 64 + u * 8) = v;
        }
    } else {
        float* outF = (float*)outv;
#pragma unroll
        for (int s = 0; s < 2; ++s) {
            int px = g * 64 + s * 32 + l31;
            int y = y0 + (px >> 4), x = x0 + (px & 15);
            size_t pbase = (size_t)b * 64 * HW + (size_t)y * 256 + x;
#pragma unroll
            for (int r = 0; r < 16; ++r) {
                int oc = w2 * 32 + (r & 3) + 8 * (r >> 2) + 4 * half;
                float v = acc2[s][r] + sB[64 + oc];
                v += res[pbase + (size_t)oc * HW];
                outF[pbase + (size_t)oc * HW] = v;
            }
        }
    }
}

// ---------------------------------------------------------------------------
// Stage: jbfm — fused kg_w5 (C->576) + dynamic-kernel combine, one 32x8 tile.
// ---------------------------------------------------------------------------
struct OffTab { unsigned v[9][32]; int chlo[9]; };
constexpr OffTab make_tab() {
    OffTab t{};
    for (int kk = 0; kk < 9; ++kk) {
        int chlo = (kk * 64) / 9;
        t.chlo[kk] = chlo;
        for (int ot = 0; ot < 2; ++ot)
            for (int r = 0; r < 16; ++r) {
                int cc0 = ot * 32 + (r & 3) + 8 * (r >> 2);
                int q0 = kk * 64 + cc0, q1 = q0 + 4;
                int o0 = (q0 / 9 - chlo) * 360 + (q0 % 9 / 3) * 40 + (q0 % 9 % 3);
                int o1 = (q1 / 9 - chlo) * 360 + (q1 % 9 / 3) * 40 + (q1 % 9 % 3);
                t.v[kk][ot * 16 + r] = (unsigned)o0 | ((unsigned)o1 << 16);
            }
    }
    return t;
}
__constant__ OffTab kOff = make_tab();

__device__ __forceinline__ void st_jbfm(char* smem, int tid, int t,
    const unsigned short* y4, const float* img,
    const unsigned short* w5T, const float* b5, unsigned short* out)
{
    uint4* sY = (uint4*)smem;                    // 2304 uint4
    float* sB5 = (float*)(smem + 76288);
    unsigned short* sT16 = (unsigned short*)smem;

    int wv = tid >> 6, lane = tid & 63;
    int half = lane >> 5, l31 = lane & 31;
    int b = t >> 8, rem = t & 255;
    int y0 = (rem >> 3) * 8, x0 = (rem & 7) * 32;
    size_t zbase = (size_t)b * HW * 64;
    size_t ibase = (size_t)b * 64 * HW;

    __syncthreads();

    int p_off[3], p_dst[3];
    bool p_a[3], p_b[3], p_act[3];
#pragma unroll
    for (int i = 0; i < 3; ++i) {
        int e = i * 256 + tid;
        bool act = e < 720;
        int ch = e / 90, rem2 = e - ch * 90;
        int rp = rem2 / 10, seg = rem2 - rp * 10;
        int gy = y0 + rp - 1;
        int gxb = x0 - 4 + seg * 4;
        bool xok = (gxb >= 0 && gxb < 256);
        p_act[i] = act;
        p_a[i] = act && xok && gy >= 0 && gy < 256;
        p_b[i] = act && xok && (gy + 1) < 256;
        p_off[i] = ch * HW + gy * 256 + gxb;
        p_dst[i] = ch * 360 + rp * 40 + seg * 4;
    }

#pragma unroll
    for (int i = 0; i < 8; ++i) {
        int e = i * 256 + tid;
        int px = e >> 3, ig = e & 7;
        int gy = y0 + (px >> 5), gx = x0 + (px & 31);
        sY[px * 9 + ig] = *(const uint4*)(y4 + zbase + ((size_t)(gy * 256 + gx)) * 64 + ig * 8);
    }
    for (int e = tid; e < 576; e += 256) sB5[e] = b5[e];

    {
        uint4* sW50 = (uint4*)(smem + 36864);
        unsigned* sP0 = (unsigned*)(smem + 53248);
#pragma unroll
        for (int u = 0; u < 2; ++u) {
            int uu = u * 256 + tid;
            int cc = uu & 63, ig = uu >> 6;
            sW50[uu] = ((const uint4*)w5T)[cc * 8 + ig];
        }
        const float* rp0 = img + ibase;
#pragma unroll
        for (int i = 0; i < 3; ++i) {
            float4 fa = make_float4(0, 0, 0, 0), fb = make_float4(0, 0, 0, 0);
            if (p_a[i]) fa = *(const float4*)(rp0 + p_off[i]);
            if (p_b[i]) fb = *(const float4*)(rp0 + p_off[i] + 256);
            if (p_act[i]) {
                uint4 pk;
                pk.x = (unsigned)f2bf(fa.x) | ((unsigned)f2bf(fb.x) << 16);
                pk.y = (unsigned)f2bf(fa.y) | ((unsigned)f2bf(fb.y) << 16);
                pk.z = (unsigned)f2bf(fa.z) | ((unsigned)f2bf(fb.z) << 16);
                pk.w = (unsigned)f2bf(fa.w) | ((unsigned)f2bf(fb.w) << 16);
                *(uint4*)&sP0[p_dst[i]] = pk;
            }
        }
    }

    float jb[2][2][16];
#pragma unroll
    for (int i = 0; i < 2; ++i)
#pragma unroll
        for (int j = 0; j < 2; ++j)
#pragma unroll
            for (int r = 0; r < 16; ++r) jb[i][j][r] = 0.f;

    __syncthreads();

#pragma unroll 1
    for (int kk = 0; kk < 9; ++kk) {
        const int cur = kk & 1;
        const uint4* sW5c = (const uint4*)(smem + 36864 + cur * 8192);
        const unsigned* sPc = (const unsigned*)(smem + 53248 + cur * 11520);

        uint4 wpre0, wpre1;
        float4 pfa[3], pfb[3];
        if (kk < 8) {
            const int nk = kk + 1;
            const int chlo_n = kOff.chlo[nk];
            {
                int cc = tid & 63, ig = tid >> 6;
                wpre0 = ((const uint4*)w5T)[(nk * 64 + cc) * 8 + ig];
                int uu = 256 + tid;
                int cc1 = uu & 63, ig1 = uu >> 6;
                wpre1 = ((const uint4*)w5T)[(nk * 64 + cc1) * 8 + ig1];
            }
            const float* rp0 = img + ibase + (size_t)chlo_n * HW;
#pragma unroll
            for (int i = 0; i < 3; ++i) {
                pfa[i] = make_float4(0, 0, 0, 0);
                pfb[i] = make_float4(0, 0, 0, 0);
                if (p_a[i]) pfa[i] = *(const float4*)(rp0 + p_off[i]);
                if (p_b[i]) pfb[i] = *(const float4*)(rp0 + p_off[i] + 256);
            }
        }

        f32x16 acc[2][2];
#pragma unroll
        for (int ot = 0; ot < 2; ++ot)
#pragma unroll
            for (int r = 0; r < 16; ++r) {
                int cc0 = ot * 32 + (r & 3) + 8 * (r >> 2);
                float bv = sB5[kk * 64 + cc0 + 4 * half];
                acc[ot][0][r] = bv;
                acc[ot][1][r] = bv;
            }

#pragma unroll
        for (int c = 0; c < 4; ++c) {
            int ig = c * 2 + half;
            bf16x8 a0 = ld_frag(&sW5c[ig * 64 + l31]);
            bf16x8 a1 = ld_frag(&sW5c[ig * 64 + 32 + l31]);
            int p0 = wv * 64 + l31;
            bf16x8 b0 = ld_frag(&sY[p0 * 9 + ig]);
            bf16x8 b1 = ld_frag(&sY[(p0 + 32) * 9 + ig]);
            acc[0][0] = __builtin_amdgcn_mfma_f32_32x32x16_bf16(a0, b0, acc[0][0], 0, 0, 0);
            acc[0][1] = __builtin_amdgcn_mfma_f32_32x32x16_bf16(a0, b1, acc[0][1], 0, 0, 0);
            acc[1][0] = __builtin_amdgcn_mfma_f32_32x32x16_bf16(a1, b0, acc[1][0], 0, 0, 0);
            acc[1][1] = __builtin_amdgcn_mfma_f32_32x32x16_bf16(a1, b1, acc[1][1], 0, 0, 0);
        }

        {
            const unsigned* basep = sPc + wv * 80 + l31 + 3;
            const unsigned* tab = kOff.v[kk];
#pragma unroll
            for (int ot = 0; ot < 2; ++ot)
#pragma unroll
                for (int r = 0; r < 16; ++r) {
                    unsigned oo = tab[ot * 16 + r];
                    unsigned o0 = oo & 0xffffu, o1 = oo >> 16;
                    unsigned pv = basep[half ? o1 : o0];
                    jb[ot][0][r] = fmaf(acc[ot][0][r], bflo2f(pv), jb[ot][0][r]);
                    jb[ot][1][r] = fmaf(acc[ot][1][r], bfhi2f(pv), jb[ot][1][r]);
                }
        }

        if (kk < 8) {
            uint4* sW5n = (uint4*)(smem + 36864 + (cur ^ 1) * 8192);
            unsigned* sPn = (unsigned*)(smem + 53248 + (cur ^ 1) * 11520);
            sW5n[tid] = wpre0;
            sW5n[256 + tid] = wpre1;
#pragma unroll
            for (int i = 0; i < 3; ++i) {
                if (p_act[i]) {
                    uint4 pk;
                    pk.x = (unsigned)f2bf(pfa[i].x) | ((unsigned)f2bf(pfb[i].x) << 16);
                    pk.y = (unsigned)f2bf(pfa[i].y) | ((unsigned)f2bf(pfb[i].y) << 16);
                    pk.z = (unsigned)f2bf(pfa[i].z) | ((unsigned)f2bf(pfb[i].z) << 16);
                    pk.w = (unsigned)f2bf(pfa[i].w) | ((unsigned)f2bf(pfb[i].w) << 16);
                    *(uint4*)&sPn[p_dst[i]] = pk;
                }
            }
        }
        __syncthreads();
    }

#pragma unroll
    for (int ot = 0; ot < 2; ++ot)
#pragma unroll
        for (int pt = 0; pt < 2; ++pt) {
            int px = wv * 64 + pt * 32 + l31;
#pragma unroll
            for (int q2 = 0; q2 < 4; ++q2) {
                unsigned short hw[4];
#pragma unroll
                for (int j = 0; j < 4; ++j) {
                    int r = (q2 << 2) | j;
                    hw[j] = f2bf(jb[ot][pt][r]);
                }
                int up = (ot * 4 + q2) ^ (px & 7);
                uint2* p = (uint2*)&sT16[px * 64 + up * 8 + half * 4];
                *p = make_uint2((unsigned)hw[0] | ((unsigned)hw[1] << 16),
                                (unsigned)hw[2] | ((unsigned)hw[3] << 16));
            }
        }
    __syncthreads();
#pragma unroll
    for (int k = 0; k < 8; ++k) {
        int col = tid >> 3, u = tid & 7;
        int px = k * 32 + col;
        uint4 v = *(uint4*)&sT16[px * 64 + (u ^ (px & 7)) * 8];
        *(uint4*)(out + zbase + ((size_t)((y0 + k) * 256 + x0 + col)) * 64 + u * 8) = v;
    }
}

// ---------------------------------------------------------------------------
// Persistent cooperative megakernel: fusem -> conv2x -> conv2x -> jbfm -> conv2x.
// 512 blocks (2/CU), XCD-slab tile mapping (slab=bid&7 owns 64 image rows of
// one batch, consistent across stages -> inter-stage reads hit own-XCD L2).
// Buffers: S1->bufA, S2->dout(bf16 scratch), S3->imgT, S4->gdT, S5->out(fp32).
// No region is read after a cross-XCD rewrite => no acquire-invalidate needed.
// ---------------------------------------------------------------------------
__global__ __launch_bounds__(256, 2) void k_mega(
    unsigned short* imgT, unsigned short* gdT, const unsigned short* wT,
    const float* tb, const float* ajbf, const float* akg,
    const float* kb1, const float* kb2, const float* kb3, const float* kb4,
    const float* kb5, const float* jb1, const float* jb2,
    const float* img, unsigned short* bufA, void* dout,
    unsigned long long* bar)
{
    __shared__ __align__(16) char smem[78592];
    int tid = threadIdx.x;
    int bid = blockIdx.x;
    int slab = bid & 7, sub = bid >> 3;

    // S1: fusem (imgT,gdT -> bufA)
#pragma unroll 1
    for (int j = 0; j < 2; ++j)
        st_fusem(smem, tid, slab * 128 + j * 64 + sub, imgT, gdT,
                 (const uint4*)(wT + (size_t)7 * 36864), tb, ajbf, bufA);
    gbar(bar, true);

    // S2: conv2x kg1+kg2 (bufA -> dout bf16 scratch)
#pragma unroll 1
    for (int j = 0; j < 2; ++j)
        st_conv2x<0>(smem, tid, slab * 128 + j * 64 + sub, bufA,
                     (const uint4*)wT, (const uint4*)(wT + (size_t)1 * 36864),
                     kb1, kb2, akg, nullptr, dout);
    gbar(bar, true);

    // S3: conv2x kg3+kg4 (dout -> imgT)
#pragma unroll 1
    for (int j = 0; j < 2; ++j)
        st_conv2x<0>(smem, tid, slab * 128 + j * 64 + sub,
                     (const unsigned short*)dout,
                     (const uint4*)(wT + (size_t)2 * 36864), (const uint4*)(wT + (size_t)3 * 36864),
                     kb3, kb4, akg, nullptr, imgT);
    gbar(bar, false);   // S4 reads imgT own-slab exact only -> no cross-XCD hand-off

    // S4: jbfm (imgT, img -> gdT)
    st_jbfm(smem, tid, slab * 64 + sub, imgT, img,
            wT + (size_t)6 * 36864, kb5, gdT);
    gbar(bar, true);

    // S5: conv2x jbf1+jbf2 + residual (gdT -> out fp32 NCHW)
#pragma unroll 1
    for (int j = 0; j < 2; ++j)
        st_conv2x<2>(smem, tid, slab * 128 + j * 64 + sub, gdT,
                     (const uint4*)(wT + (size_t)4 * 36864), (const uint4*)(wT + (size_t)5 * 36864),
                     jb1, jb2, ajbf, img, dout);
}

// ---------------------------------------------------------------------------
extern "C" void kernel_launch(void* const* d_in, const int* in_sizes, int n_in,
                              void* d_out, int out_size, void* d_ws, size_t ws_size,
                              hipStream_t stream) {
    const float* img  = (const float*)d_in[0];
    const float* gd   = (const float*)d_in[1];
    const float* tw   = (const float*)d_in[2];
    const float* tb   = (const float*)d_in[3];
    const float* ajbf = (const float*)d_in[4];
    const float* kw1  = (const float*)d_in[5];
    const float* kb1  = (const float*)d_in[6];
    const float* kw2  = (const float*)d_in[7];
    const float* kb2  = (const float*)d_in[8];
    const float* kw3  = (const float*)d_in[9];
    const float* kb3  = (const float*)d_in[10];
    const float* kw4  = (const float*)d_in[11];
    const float* kb4  = (const float*)d_in[12];
    const float* kw5  = (const float*)d_in[13];
    const float* kb5  = (const float*)d_in[14];
    const float* akg  = (const float*)d_in[15];
    const float* jw1  = (const float*)d_in[16];
    const float* jb1  = (const float*)d_in[17];
    const float* jw2  = (const float*)d_in[18];
    const float* jb2  = (const float*)d_in[19];

    const size_t TEN = (size_t)2 * HW * 64;      // elements per bf16 tensor
    unsigned short* bufA = (unsigned short*)d_ws;
    unsigned short* imgT = bufA + TEN;
    unsigned short* gdT  = imgT + TEN;
    unsigned short* wT   = gdT + TEN;
    unsigned long long* bar = (unsigned long long*)(wT + (size_t)8 * 36864);
    void* doutv = d_out;

    k_tr<<<dim3(1024, 4), 256, 0, stream>>>(img, gd, imgT, gdT);
    k_wprep<<<dim3(4, 8), 256, 0, stream>>>(kw1, kw2, kw3, kw4, jw1, jw2, kw5, tw, wT, bar);

    const unsigned short* wTc = wT;
    const float* imgc = img;
    void* kargs[] = {
        (void*)&imgT, (void*)&gdT, (void*)&wTc,
        (void*)&tb, (void*)&ajbf, (void*)&akg,
        (void*)&kb1, (void*)&kb2, (void*)&kb3, (void*)&kb4,
        (void*)&kb5, (void*)&jb1, (void*)&jb2,
        (void*)&imgc, (void*)&bufA, (void*)&doutv, (void*)&bar
    };
    if (hipLaunchCooperativeKernel((void*)k_mega, dim3(512), dim3(256),
                                   kargs, 0, stream) != hipSuccess) {
        // fallback: plain launch (512 blocks = exact 2/CU capacity, co-resident)
        k_mega<<<dim3(512), dim3(256), 0, stream>>>(
            imgT, gdT, wTc, tb, ajbf, akg, kb1, kb2, kb3, kb4,
            kb5, jb1, jb2, imgc, bufA, doutv, bar);
    }
}

// Round 7
// 303.095 us; speedup vs baseline: 2.5160x; 2.5160x over previous
//
#include <hip/hip_runtime.h>

#define HW 65536

typedef __bf16 bf16x8 __attribute__((ext_vector_type(8)));
typedef float f32x16 __attribute__((ext_vector_type(16)));

__device__ inline unsigned short f2bf(float x) {
    union { float f; unsigned u; } v; v.f = x;
    unsigned r = v.u + 0x7FFF + ((v.u >> 16) & 1);   // RNE
    return (unsigned short)(r >> 16);
}
__device__ inline float bfhi2f(unsigned u) {        // high 16 bits as f32
    union { unsigned u; float f; } v; v.u = u & 0xffff0000u; return v.f;
}
__device__ inline float bflo2f(unsigned u) {        // low 16 bits as f32
    union { unsigned u; float f; } v; v.u = u << 16; return v.f;
}

union FragU { uint4 u; bf16x8 v; };
__device__ inline bf16x8 ld_frag(const uint4* p) { FragU t; t.u = *p; return t.v; }

// XCD-slab swizzle: XCD = lin & 7 (dispatch round-robin). Slab s owns a
// contiguous 64-row band of one batch: b = s>>2, rows [(s&3)*64, +64).
// Per-XCD L2 working set ~2.1MB (fits 4MB) -> halo/re-reads become L2 hits.

// ---------------------------------------------------------------------------
// Weight pre-transform.
// y<6  : 3x3 conv weights -> fragment-linear [(tap*8+igg)*64+oc]*8+j  (igg=ic>>3)
// y==6 : kg_w5 combine layout (consumed by k_jbfm)
// y==7 : tensor 1x1 weights -> [kg*64+oc]*8+j (direct A-frag reads in k_fusem)
// ---------------------------------------------------------------------------
__global__ __launch_bounds__(256) void k_wprep(
    const float* __restrict__ w0, const float* __restrict__ w1,
    const float* __restrict__ w2, const float* __restrict__ w3,
    const float* __restrict__ w4, const float* __restrict__ w5,
    const float* __restrict__ w5c, const float* __restrict__ tw,
    unsigned short* __restrict__ wT)
{
    int y = blockIdx.y;
    unsigned short* o = wT + (size_t)y * 36864;
    if (y < 6) {
        const float* ws_[6] = {w0, w1, w2, w3, w4, w5};
        const float* w = ws_[y];
        for (int e = blockIdx.x * 256 + threadIdx.x; e < 36864; e += gridDim.x * 256) {
            int tap = e >> 12, oc = (e >> 6) & 63, ic = e & 63;
            int igg = ic >> 3, j = ic & 7;
            int dst = ((tap * 8 + igg) * 64 + oc) * 8 + j;
            o[dst] = f2bf(w[(oc * 64 + ic) * 9 + tap]);
        }
    } else if (y == 6) {
        for (int e = blockIdx.x * 256 + threadIdx.x; e < 36864; e += gridDim.x * 256)
            o[e] = f2bf(w5c[e]);
    } else {
        for (int e = blockIdx.x * 256 + threadIdx.x; e < 8192; e += gridDim.x * 256) {
            int oc = e >> 7, ic = e & 127;
            int kg = ic >> 3, j = ic & 7;
            o[((kg * 64 + oc) << 3) + j] = f2bf(tw[e]);
        }
    }
}

// ---------------------------------------------------------------------------
// k_tr: NCHW fp32 -> NHWC bf16 for img and guidance (64-px x 64-ch tiles).
// ---------------------------------------------------------------------------
__global__ __launch_bounds__(256) void k_tr(
    const float* __restrict__ img, const float* __restrict__ gd,
    unsigned short* __restrict__ imgT, unsigned short* __restrict__ gdT)
{
    __shared__ float sT[64 * 66];   // [ic][66] fp32 (stride 66 -> spread reads)
    int tid = threadIdx.x;
    int z = blockIdx.y;             // tensor*2 + b
    int b = z & 1;
    const float* src = (z >> 1) ? gd : img;
    unsigned short* dst = (z >> 1) ? gdT : imgT;
    int px0 = blockIdx.x * 64;
    size_t sbase = (size_t)b * 64 * HW + px0;

#pragma unroll
    for (int i = 0; i < 4; ++i) {
        int e = i * 256 + tid;                 // [0,1024)
        int ic = e >> 4, seg = e & 15;
        float4 v = *(const float4*)(src + sbase + (size_t)ic * HW + seg * 4);
        float* p = &sT[ic * 66 + seg * 4];
        ((float2*)p)[0] = make_float2(v.x, v.y);
        ((float2*)p)[1] = make_float2(v.z, v.w);
    }
    __syncthreads();

    size_t dbase = (size_t)b * HW * 64 + (size_t)px0 * 64;
#pragma unroll
    for (int k = 0; k < 2; ++k) {
        int idx = k * 256 + tid;               // [0,512)
        int px = idx >> 3, u = idx & 7;
        union { uint4 q; unsigned short h[8]; } o;
#pragma unroll
        for (int j = 0; j < 8; ++j)
            o.h[j] = f2bf(sT[(u * 8 + j) * 66 + px]);
        *(uint4*)(dst + dbase + (size_t)px * 64 + u * 8) = o.q;
    }
}

// ---------------------------------------------------------------------------
// k_fusem: 1x1 (2C->C) + PReLU. NHWC bf16 in (imgT, gdT), NHWC bf16 out.
// 16x8 px tile, XCD-slab swizzled, direct-global weight frags,
// h1 tile prefetched into regs during compute(h0).
// ---------------------------------------------------------------------------
__global__ __launch_bounds__(256, 4) void k_fusem(
    const unsigned short* __restrict__ imgT, const unsigned short* __restrict__ gdT,
    const unsigned short* __restrict__ wTf, const float* __restrict__ bias,
    const float* __restrict__ a, unsigned short* __restrict__ out)
{
    __shared__ __align__(16) char smem[18688];
    uint4* sX = (uint4*)smem;                     // 1152 uint4: [px][ig 0..8(pad)]
    float* sB = (float*)(smem + 18432);
    unsigned short* sT16 = (unsigned short*)smem; // epilogue overlay 16KB

    int tid = threadIdx.x;
    int wv = tid >> 6, lane = tid & 63;
    int half = lane >> 5, l31 = lane & 31;
    int lin = blockIdx.x + (blockIdx.y << 4) + (blockIdx.z << 9);  // [0,1024)
    int slab = lin & 7, sub = lin >> 3;           // sub in [0,128)
    int b = slab >> 2;
    int y0 = (slab & 3) * 64 + (sub >> 4) * 8;
    int x0 = (sub & 15) * 16;
    size_t zbase = (size_t)b * HW * 64;
    const uint4* wg = (const uint4*)wTf;          // [kg*64+oc]

    if (tid < 64) sB[tid] = bias[tid];

    f32x16 acc[2];
#pragma unroll
    for (int i = 0; i < 2; ++i)
#pragma unroll
        for (int r = 0; r < 16; ++r) acc[i][r] = 0.f;

    auto loadX = [&](const unsigned short* src, uint4* rx) {
#pragma unroll
        for (int i = 0; i < 4; ++i) {
            int e = i * 256 + tid;                 // [0,1024)
            int px = e >> 3, ig = e & 7;
            int gy = y0 + (px >> 4), gx = x0 + (px & 15);
            rx[i] = *(const uint4*)(src + zbase + ((size_t)(gy * 256 + gx)) * 64 + ig * 8);
        }
    };
    auto writeX = [&](const uint4* rx) {
#pragma unroll
        for (int i = 0; i < 4; ++i) {
            int e = i * 256 + tid;
            sX[(e >> 3) * 9 + (e & 7)] = rx[i];
        }
    };
    auto compute = [&](int h) {
#pragma unroll
        for (int c = 0; c < 4; ++c) {
            int ig = c * 2 + half;
            int kg = h * 8 + ig;
            bf16x8 a0 = ld_frag(&wg[kg * 64 + l31]);
            bf16x8 a1 = ld_frag(&wg[kg * 64 + 32 + l31]);
            int p0 = wv * 32 + l31;
            bf16x8 b0 = ld_frag(&sX[p0 * 9 + ig]);
            acc[0] = __builtin_amdgcn_mfma_f32_32x32x16_bf16(a0, b0, acc[0], 0, 0, 0);
            acc[1] = __builtin_amdgcn_mfma_f32_32x32x16_bf16(a1, b0, acc[1], 0, 0, 0);
        }
    };

    uint4 rx[4], ry[4];
    loadX(imgT, rx);
    writeX(rx);
    loadX(gdT, ry);        // prefetch h1 (in flight across compute h0)
    __syncthreads();
    compute(0);
    __syncthreads();
    writeX(ry);
    __syncthreads();
    compute(1);

    float slope = a[0];
    __syncthreads();   // before overwriting sX region with epilogue tile
    {
        int px = wv * 32 + l31;
#pragma unroll
        for (int ot = 0; ot < 2; ++ot)
#pragma unroll
            for (int q2 = 0; q2 < 4; ++q2) {
                unsigned short hw[4];
#pragma unroll
                for (int j = 0; j < 4; ++j) {
                    int r = (q2 << 2) | j;
                    int oc = ot * 32 + j + 8 * q2 + 4 * half;
                    float v = acc[ot][r] + sB[oc];
                    v = (v >= 0.f) ? v : slope * v;
                    hw[j] = f2bf(v);
                }
                int unit = ot * 4 + q2;
                int up = unit ^ (px & 7);
                uint2* p = (uint2*)&sT16[px * 64 + up * 8 + half * 4];
                *p = make_uint2((unsigned)hw[0] | ((unsigned)hw[1] << 16),
                                (unsigned)hw[2] | ((unsigned)hw[3] << 16));
            }
    }
    __syncthreads();
#pragma unroll
    for (int k = 0; k < 4; ++k) {
        int idx = k * 256 + tid;               // [0,1024)
        int row = idx >> 7, rem = idx & 127;
        int col = rem >> 3, u = rem & 7;
        int px = row * 16 + col;
        uint4 v = *(uint4*)&sT16[px * 64 + (u ^ (px & 7)) * 8];
        *(uint4*)(out + zbase + ((size_t)((y0 + row) * 256 + x0 + col)) * 64 + u * 8) = v;
    }
}

// ---------------------------------------------------------------------------
// k_conv2x: FUSED pair of 3x3 convs C=64->64 pad 1, bf16 MFMA, NHWC bf16 in.
// XCD-slab swizzled 16x8 tiles. oc-split wave assignment (w2,g); A-frag loads
// 72/wave, reused 2-3x; fully unrolled taps for ILP.
// conv1 on 18x10 output-halo (bias1+PReLU, OOB cells zeroed) -> LDS
// (XOR-swizzled [cell][unit]) -> conv2 16x8 output tile.
// MODE 0: PReLU after conv2, NHWC bf16 out.
// MODE 2: no final PReLU, + fp32 residual, NCHW fp32 out.
// ---------------------------------------------------------------------------
#define XU 5

template<int MODE>
__global__ __launch_bounds__(256, 4) void k_conv2x(
    const unsigned short* __restrict__ in,
    const unsigned short* __restrict__ w1T, const unsigned short* __restrict__ w2T,
    const float* __restrict__ b1, const float* __restrict__ b2,
    const float* __restrict__ a, const float* __restrict__ res,
    void* __restrict__ outv)
{
    __shared__ __align__(16) char smem[38912];
    uint4* sIn0 = (uint4*)smem;                    // 1200 uint4: 240 cells x XU
    uint4* sIn1 = (uint4*)(smem + 19200);          // 1200 uint4 (h=1)
    float* sB = (float*)(smem + 38400);            // [0..63]=b1, [64..127]=b2
    // overlays (after barriers): sC 23040B @0 (conv1 out), sT16 16KB @0 (epilogue)

    int tid = threadIdx.x;
    int wv = tid >> 6, lane = tid & 63;
    int half = lane >> 5, l31 = lane & 31;
    int w2 = wv >> 1, g = wv & 1;                  // oc-half, px-group
    int lin = blockIdx.x + (blockIdx.y << 4) + (blockIdx.z << 9);  // [0,1024)
    int slab = lin & 7, sub = lin >> 3;            // sub in [0,128)
    int b = slab >> 2;
    int y0 = (slab & 3) * 64 + (sub >> 4) * 8;
    int x0 = (sub & 15) * 16;
    const size_t zbase = (size_t)b * HW * 64;
    const uint4* wg1 = (const uint4*)w1T;          // [(tap*8+igg)*64+oc]
    const uint4* wg2 = (const uint4*)w2T;

    if (tid < 64) sB[tid] = b1[tid];
    else if (tid < 128) sB[tid] = b2[tid - 64];

    // input halo: 12 rows x 20 cols, origin (y0-2, x0-2)
    auto loadIn = [&](int h, uint4* rx) {
#pragma unroll
        for (int i = 0; i < 4; ++i) {
            int e = i * 256 + tid;                 // [0,1024), active < 960
            int cell = e >> 2, ig = e & 3;
            int r = cell / 20, c2 = cell - r * 20;
            int gy = y0 - 2 + r, gx = x0 - 2 + c2;
            rx[i] = make_uint4(0, 0, 0, 0);
            bool act = (i < 3) || (e < 960);
            if (act && gy >= 0 && gy < 256 && gx >= 0 && gx < 256)
                rx[i] = *(const uint4*)(in + zbase + ((size_t)(gy * 256 + gx)) * 64 + h * 32 + ig * 8);
        }
    };
    auto writeIn = [&](uint4* s, const uint4* rx) {
#pragma unroll
        for (int i = 0; i < 4; ++i) {
            int e = i * 256 + tid;
            if (i < 3 || e < 960) s[(e >> 2) * XU + (e & 3)] = rx[i];
        }
    };

    // conv1 cells: 180 over [10 rows][18 cols] output-halo grid.
    // this wave: cells g*96 + s*32 + l31, s=0..2 (clamped addressing >=180)
    int cellv[3], ibv[3];
#pragma unroll
    for (int s = 0; s < 3; ++s) {
        int c = g * 96 + s * 32 + l31;
        cellv[s] = c;
        int cc = c < 180 ? c : 179;
        ibv[s] = (cc / 18) * 20 + (cc % 18);
    }

    f32x16 acc1[3];
#pragma unroll
    for (int s = 0; s < 3; ++s)
#pragma unroll
        for (int r = 0; r < 16; ++r) acc1[s][r] = 0.f;

    auto conv1_h = [&](int h, const uint4* sInp) {
#pragma unroll
        for (int dy = 0; dy < 3; ++dy) {
#pragma unroll
            for (int dx = 0; dx < 3; ++dx) {
                int tap = dy * 3 + dx;
                int doff = dy * 20 + dx;
#pragma unroll
                for (int c = 0; c < 2; ++c) {
                    int ig = c * 2 + half;
                    bf16x8 af = ld_frag(&wg1[(tap * 8 + h * 4 + ig) * 64 + w2 * 32 + l31]);
#pragma unroll
                    for (int s = 0; s < 3; ++s) {
                        bf16x8 bb = ld_frag(&sInp[(ibv[s] + doff) * XU + ig]);
                        acc1[s] = __builtin_amdgcn_mfma_f32_32x32x16_bf16(af, bb, acc1[s], 0, 0, 0);
                    }
                }
            }
        }
    };

    uint4 rx[4];
    loadIn(0, rx);
    writeIn(sIn0, rx);
    uint4 ry[4];
    loadIn(1, ry);          // prefetch h1 (latency hidden under conv1 h0)
    __syncthreads();
    conv1_h(0, sIn0);
    writeIn(sIn1, ry);
    __syncthreads();
    conv1_h(1, sIn1);

    // conv1 epilogue: bias+PReLU, zero out-of-image cells, pack bf16 to sC
    float s1 = a[0];
    __syncthreads();        // all sIn reads done; sC overlays sIn0
    unsigned short* sC16 = (unsigned short*)smem;
#pragma unroll
    for (int s = 0; s < 3; ++s) {
        int cell = cellv[s];
        if (cell < 180) {
            int orow = cell / 18, ocol = cell - orow * 18;
            int gy = y0 - 1 + orow, gx = x0 - 1 + ocol;
            bool inb = (gy >= 0 && gy < 256 && gx >= 0 && gx < 256);
#pragma unroll
            for (int q2 = 0; q2 < 4; ++q2) {
                unsigned short hw[4];
#pragma unroll
                for (int j = 0; j < 4; ++j) {
                    int r = (q2 << 2) | j;
                    int oc = w2 * 32 + j + 8 * q2 + 4 * half;
                    float v = acc1[s][r] + sB[oc];
                    v = (v >= 0.f) ? v : s1 * v;
                    if (!inb) v = 0.f;
                    hw[j] = f2bf(v);
                }
                int up = (w2 * 4 + q2) ^ (cell & 7);
                *(uint2*)&sC16[cell * 64 + up * 8 + half * 4] =
                    make_uint2((unsigned)hw[0] | ((unsigned)hw[1] << 16),
                               (unsigned)hw[2] | ((unsigned)hw[3] << 16));
            }
        }
    }
    __syncthreads();        // sC ready

    // conv2: 16x8 output tile; this wave: px = g*64 + s*32 + l31 (s=0,1), oc-half w2
    f32x16 acc2[2];
#pragma unroll
    for (int s = 0; s < 2; ++s)
#pragma unroll
        for (int r = 0; r < 16; ++r) acc2[s][r] = 0.f;

    int rowS[2], colS[2];
#pragma unroll
    for (int s = 0; s < 2; ++s) {
        int px = g * 64 + s * 32 + l31;
        rowS[s] = px >> 4; colS[s] = px & 15;
    }
    {
        const uint4* sC4 = (const uint4*)smem;
#pragma unroll
        for (int dy = 0; dy < 3; ++dy) {
#pragma unroll
            for (int dx = 0; dx < 3; ++dx) {
                int tap = dy * 3 + dx;
#pragma unroll
                for (int c = 0; c < 4; ++c) {
                    int ig = c * 2 + half;
                    bf16x8 af = ld_frag(&wg2[(tap * 8 + ig) * 64 + w2 * 32 + l31]);
#pragma unroll
                    for (int s = 0; s < 2; ++s) {
                        int cl = (rowS[s] + dy) * 18 + colS[s] + dx;
                        bf16x8 bb = ld_frag(&sC4[cl * 8 + (ig ^ (cl & 7))]);
                        acc2[s] = __builtin_amdgcn_mfma_f32_32x32x16_bf16(af, bb, acc2[s], 0, 0, 0);
                    }
                }
            }
        }
    }

    if (MODE == 0) {
        __syncthreads();    // conv2 reads done; sT16 overlays sC
        unsigned short* sT16 = (unsigned short*)smem;
#pragma unroll
        for (int s = 0; s < 2; ++s) {
            int px = g * 64 + s * 32 + l31;
#pragma unroll
            for (int q2 = 0; q2 < 4; ++q2) {
                unsigned short hw[4];
#pragma unroll
                for (int j = 0; j < 4; ++j) {
                    int r = (q2 << 2) | j;
                    int oc = w2 * 32 + j + 8 * q2 + 4 * half;
                    float v = acc2[s][r] + sB[64 + oc];
                    v = (v >= 0.f) ? v : s1 * v;
                    hw[j] = f2bf(v);
                }
                int up = (w2 * 4 + q2) ^ (px & 7);
                uint2* p = (uint2*)&sT16[px * 64 + up * 8 + half * 4];
                *p = make_uint2((unsigned)hw[0] | ((unsigned)hw[1] << 16),
                                (unsigned)hw[2] | ((unsigned)hw[3] << 16));
            }
        }
        __syncthreads();
        unsigned short* outT = (unsigned short*)outv;
#pragma unroll
        for (int k = 0; k < 4; ++k) {
            int idx = k * 256 + tid;
            int row = idx >> 7, rem = idx & 127;
            int col = rem >> 3, u = rem & 7;
            int px = row * 16 + col;
            uint4 v = *(uint4*)&sT16[px * 64 + (u ^ (px & 7)) * 8];
            *(uint4*)(outT + zbase + ((size_t)((y0 + row) * 256 + x0 + col)) * 64 + u * 8) = v;
        }
    } else {
        // final conv: + residual, fp32 NCHW out (no PReLU after conv2)
        float* outF = (float*)outv;
#pragma unroll
        for (int s = 0; s < 2; ++s) {
            int px = g * 64 + s * 32 + l31;
            int y = y0 + (px >> 4), x = x0 + (px & 15);
            size_t pbase = (size_t)b * 64 * HW + (size_t)y * 256 + x;
#pragma unroll
            for (int r = 0; r < 16; ++r) {
                int oc = w2 * 32 + (r & 3) + 8 * (r >> 2) + 4 * half;
                float v = acc2[s][r] + sB[64 + oc];
                v += res[pbase + (size_t)oc * HW];
                outF[pbase + (size_t)oc * HW] = v;
            }
        }
    }
}

// ---------------------------------------------------------------------------
// k_jbfm: fused kg_w5 (C->576) + dynamic-kernel combine.
// XCD-slab swizzled 32x8 tiles. Rolled kk loop + double-buffered sP/sW5 with
// register prefetch (round 1).
// ---------------------------------------------------------------------------
struct OffTab { unsigned v[9][32]; int chlo[9]; };
constexpr OffTab make_tab() {
    OffTab t{};
    for (int kk = 0; kk < 9; ++kk) {
        int chlo = (kk * 64) / 9;
        t.chlo[kk] = chlo;
        for (int ot = 0; ot < 2; ++ot)
            for (int r = 0; r < 16; ++r) {
                int cc0 = ot * 32 + (r & 3) + 8 * (r >> 2);
                int q0 = kk * 64 + cc0, q1 = q0 + 4;
                int o0 = (q0 / 9 - chlo) * 360 + (q0 % 9 / 3) * 40 + (q0 % 9 % 3);
                int o1 = (q1 / 9 - chlo) * 360 + (q1 % 9 / 3) * 40 + (q1 % 9 % 3);
                t.v[kk][ot * 16 + r] = (unsigned)o0 | ((unsigned)o1 << 16);
            }
    }
    return t;
}
__constant__ OffTab kOff = make_tab();

__global__ __launch_bounds__(256, 2) void k_jbfm(
    const unsigned short* __restrict__ y4, const float* __restrict__ img,
    const unsigned short* __restrict__ w5T, const float* __restrict__ b5,
    unsigned short* __restrict__ out)
{
    __shared__ __align__(16) char smem[78592];
    uint4* sY = (uint4*)smem;                    // 2304 uint4: [px][ig 0..8(pad)]
    // sW5 double buffer: 2 x 512 uint4 at 36864 / 45056
    // sP  double buffer: 2 x 2880 u32  at 53248 / 64768
    float* sB5 = (float*)(smem + 76288);         // 576 f32
    unsigned short* sT16 = (unsigned short*)smem;// epilogue overlay 32KB

    int tid = threadIdx.x;
    int wv = tid >> 6, lane = tid & 63;
    int half = lane >> 5, l31 = lane & 31;
    int lin = blockIdx.x + (blockIdx.y << 3) + (blockIdx.z << 8);  // [0,512)
    int slab = lin & 7, sub = lin >> 3;          // sub in [0,64)
    int b = slab >> 2;
    int y0 = (slab & 3) * 64 + (sub >> 3) * 8;
    int x0 = (sub & 7) * 32;
    size_t zbase = (size_t)b * HW * 64;          // NHWC base
    size_t ibase = (size_t)b * 64 * HW;          // NCHW base (img)

    // kk-invariant staging descriptors (720 pack-items over 256 threads)
    int p_off[3], p_dst[3];
    bool p_a[3], p_b[3], p_act[3];
#pragma unroll
    for (int i = 0; i < 3; ++i) {
        int e = i * 256 + tid;
        bool act = e < 720;
        int ch = e / 90, rem = e - ch * 90;
        int rp = rem / 10, seg = rem - rp * 10;
        int gy = y0 + rp - 1;
        int gxb = x0 - 4 + seg * 4;
        bool xok = (gxb >= 0 && gxb < 256);
        p_act[i] = act;
        p_a[i] = act && xok && gy >= 0 && gy < 256;
        p_b[i] = act && xok && (gy + 1) < 256;   // gy+1 >= 0 always (gy >= -1)
        p_off[i] = ch * HW + gy * 256 + gxb;     // element offset; +256 for row+1
        p_dst[i] = ch * 360 + rp * 40 + seg * 4;
    }

    // stage y4 tile: 2048 uint4, NHWC (reused by every kk)
#pragma unroll
    for (int i = 0; i < 8; ++i) {
        int e = i * 256 + tid;
        int px = e >> 3, ig = e & 7;
        int gy = y0 + (px >> 5), gx = x0 + (px & 31);
        sY[px * 9 + ig] = *(const uint4*)(y4 + zbase + ((size_t)(gy * 256 + gx)) * 64 + ig * 8);
    }
    for (int e = tid; e < 576; e += 256) sB5[e] = b5[e];

    // prologue: stage kk=0 into buffer 0 (chlo(0) = 0)
    {
        uint4* sW50 = (uint4*)(smem + 36864);
        unsigned* sP0 = (unsigned*)(smem + 53248);
#pragma unroll
        for (int u = 0; u < 2; ++u) {
            int uu = u * 256 + tid;
            int cc = uu & 63, ig = uu >> 6;
            sW50[uu] = ((const uint4*)w5T)[cc * 8 + ig];
        }
        const float* rp0 = img + ibase;
#pragma unroll
        for (int i = 0; i < 3; ++i) {
            float4 fa = make_float4(0, 0, 0, 0), fb = make_float4(0, 0, 0, 0);
            if (p_a[i]) fa = *(const float4*)(rp0 + p_off[i]);
            if (p_b[i]) fb = *(const float4*)(rp0 + p_off[i] + 256);
            if (p_act[i]) {
                uint4 pk;
                pk.x = (unsigned)f2bf(fa.x) | ((unsigned)f2bf(fb.x) << 16);
                pk.y = (unsigned)f2bf(fa.y) | ((unsigned)f2bf(fb.y) << 16);
                pk.z = (unsigned)f2bf(fa.z) | ((unsigned)f2bf(fb.z) << 16);
                pk.w = (unsigned)f2bf(fa.w) | ((unsigned)f2bf(fb.w) << 16);
                *(uint4*)&sP0[p_dst[i]] = pk;
            }
        }
    }

    float jb[2][2][16];
#pragma unroll
    for (int i = 0; i < 2; ++i)
#pragma unroll
        for (int j = 0; j < 2; ++j)
#pragma unroll
            for (int r = 0; r < 16; ++r) jb[i][j][r] = 0.f;

    __syncthreads();

#pragma unroll 1
    for (int kk = 0; kk < 9; ++kk) {
        const int cur = kk & 1;
        const uint4* sW5c = (const uint4*)(smem + 36864 + cur * 8192);
        const unsigned* sPc = (const unsigned*)(smem + 53248 + cur * 11520);

        // ---- A: issue next iteration's global loads (hide under compute) ----
        uint4 wpre0, wpre1;
        float4 pfa[3], pfb[3];
        if (kk < 8) {
            const int nk = kk + 1;
            const int chlo_n = kOff.chlo[nk];
            {
                int cc = tid & 63, ig = tid >> 6;
                wpre0 = ((const uint4*)w5T)[(nk * 64 + cc) * 8 + ig];
                int uu = 256 + tid;
                int cc1 = uu & 63, ig1 = uu >> 6;
                wpre1 = ((const uint4*)w5T)[(nk * 64 + cc1) * 8 + ig1];
            }
            const float* rp0 = img + ibase + (size_t)chlo_n * HW;
#pragma unroll
            for (int i = 0; i < 3; ++i) {
                pfa[i] = make_float4(0, 0, 0, 0);
                pfb[i] = make_float4(0, 0, 0, 0);
                if (p_a[i]) pfa[i] = *(const float4*)(rp0 + p_off[i]);
                if (p_b[i]) pfb[i] = *(const float4*)(rp0 + p_off[i] + 256);
            }
        }

        // ---- B: compute current kk ----
        f32x16 acc[2][2];
#pragma unroll
        for (int ot = 0; ot < 2; ++ot)
#pragma unroll
            for (int r = 0; r < 16; ++r) {
                int cc0 = ot * 32 + (r & 3) + 8 * (r >> 2);
                float bv = sB5[kk * 64 + cc0 + 4 * half];
                acc[ot][0][r] = bv;
                acc[ot][1][r] = bv;
            }

#pragma unroll
        for (int c = 0; c < 4; ++c) {
            int ig = c * 2 + half;
            bf16x8 a0 = ld_frag(&sW5c[ig * 64 + l31]);
            bf16x8 a1 = ld_frag(&sW5c[ig * 64 + 32 + l31]);
            int p0 = wv * 64 + l31;
            bf16x8 b0 = ld_frag(&sY[p0 * 9 + ig]);
            bf16x8 b1 = ld_frag(&sY[(p0 + 32) * 9 + ig]);
            acc[0][0] = __builtin_amdgcn_mfma_f32_32x32x16_bf16(a0, b0, acc[0][0], 0, 0, 0);
            acc[0][1] = __builtin_amdgcn_mfma_f32_32x32x16_bf16(a0, b1, acc[0][1], 0, 0, 0);
            acc[1][0] = __builtin_amdgcn_mfma_f32_32x32x16_bf16(a1, b0, acc[1][0], 0, 0, 0);
            acc[1][1] = __builtin_amdgcn_mfma_f32_32x32x16_bf16(a1, b1, acc[1][1], 0, 0, 0);
        }

        // combine: one packed b32 read serves both pt pixels
        {
            const unsigned* basep = sPc + wv * 80 + l31 + 3;
            const unsigned* tab = kOff.v[kk];    // wave-uniform -> scalar loads
#pragma unroll
            for (int ot = 0; ot < 2; ++ot)
#pragma unroll
                for (int r = 0; r < 16; ++r) {
                    unsigned oo = tab[ot * 16 + r];
                    unsigned o0 = oo & 0xffffu, o1 = oo >> 16;
                    unsigned pv = basep[half ? o1 : o0];
                    jb[ot][0][r] = fmaf(acc[ot][0][r], bflo2f(pv), jb[ot][0][r]);
                    jb[ot][1][r] = fmaf(acc[ot][1][r], bfhi2f(pv), jb[ot][1][r]);
                }
        }

        // ---- C: pack + write prefetched data into the other buffer ----
        if (kk < 8) {
            uint4* sW5n = (uint4*)(smem + 36864 + (cur ^ 1) * 8192);
            unsigned* sPn = (unsigned*)(smem + 53248 + (cur ^ 1) * 11520);
            sW5n[tid] = wpre0;
            sW5n[256 + tid] = wpre1;
#pragma unroll
            for (int i = 0; i < 3; ++i) {
                if (p_act[i]) {
                    uint4 pk;
                    pk.x = (unsigned)f2bf(pfa[i].x) | ((unsigned)f2bf(pfb[i].x) << 16);
                    pk.y = (unsigned)f2bf(pfa[i].y) | ((unsigned)f2bf(pfb[i].y) << 16);
                    pk.z = (unsigned)f2bf(pfa[i].z) | ((unsigned)f2bf(pfb[i].z) << 16);
                    pk.w = (unsigned)f2bf(pfa[i].w) | ((unsigned)f2bf(pfb[i].w) << 16);
                    *(uint4*)&sPn[p_dst[i]] = pk;
                }
            }
        }
        __syncthreads();
    }

    // epilogue: NHWC bf16 out via swizzled LDS transpose (overlay on sY region)
#pragma unroll
    for (int ot = 0; ot < 2; ++ot)
#pragma unroll
        for (int pt = 0; pt < 2; ++pt) {
            int px = wv * 64 + pt * 32 + l31;
#pragma unroll
            for (int q2 = 0; q2 < 4; ++q2) {
                unsigned short hw[4];
#pragma unroll
                for (int j = 0; j < 4; ++j) {
                    int r = (q2 << 2) | j;
                    hw[j] = f2bf(jb[ot][pt][r]);
                }
                int unit = ot * 4 + q2;
                int up = unit ^ (px & 7);
                uint2* p = (uint2*)&sT16[px * 64 + up * 8 + half * 4];
                *p = make_uint2((unsigned)hw[0] | ((unsigned)hw[1] << 16),
                                (unsigned)hw[2] | ((unsigned)hw[3] << 16));
            }
        }
    __syncthreads();
#pragma unroll
    for (int k = 0; k < 8; ++k) {
        int col = tid >> 3, u = tid & 7;
        int px = k * 32 + col;
        uint4 v = *(uint4*)&sT16[px * 64 + (u ^ (px & 7)) * 8];
        *(uint4*)(out + zbase + ((size_t)((y0 + k) * 256 + x0 + col)) * 64 + u * 8) = v;
    }
}

// ---------------------------------------------------------------------------
extern "C" void kernel_launch(void* const* d_in, const int* in_sizes, int n_in,
                              void* d_out, int out_size, void* d_ws, size_t ws_size,
                              hipStream_t stream) {
    const float* img  = (const float*)d_in[0];
    const float* gd   = (const float*)d_in[1];
    const float* tw   = (const float*)d_in[2];
    const float* tb   = (const float*)d_in[3];
    const float* ajbf = (const float*)d_in[4];
    const float* kw1  = (const float*)d_in[5];
    const float* kb1  = (const float*)d_in[6];
    const float* kw2  = (const float*)d_in[7];
    const float* kb2  = (const float*)d_in[8];
    const float* kw3  = (const float*)d_in[9];
    const float* kb3  = (const float*)d_in[10];
    const float* kw4  = (const float*)d_in[11];
    const float* kb4  = (const float*)d_in[12];
    const float* kw5  = (const float*)d_in[13];
    const float* kb5  = (const float*)d_in[14];
    const float* akg  = (const float*)d_in[15];
    const float* jw1  = (const float*)d_in[16];
    const float* jb1  = (const float*)d_in[17];
    const float* jw2  = (const float*)d_in[18];
    const float* jb2  = (const float*)d_in[19];
    float* out  = (float*)d_out;

    const size_t TEN = (size_t)2 * HW * 64;      // elements per bf16 tensor
    unsigned short* bufA = (unsigned short*)d_ws;
    unsigned short* imgT = bufA + TEN;
    unsigned short* gdT  = imgT + TEN;           // dead after fusem -> reused as bufC
    unsigned short* wT   = gdT + TEN;
    unsigned short* bufB = (unsigned short*)d_out;   // d_out as scratch until final conv
    unsigned short* bufC = gdT;

    dim3 gs(16, 32, 2);     // conv/fuse tiles 16x8 -> 1024 blocks (slab-swizzled)
    dim3 gw(8, 32, 2);      // jbf tiles 32x8 -> 512 blocks (slab-swizzled)

    k_tr<<<dim3(1024, 4), 256, 0, stream>>>(img, gd, imgT, gdT);
    k_wprep<<<dim3(4, 8), 256, 0, stream>>>(kw1, kw2, kw3, kw4, jw1, jw2, kw5, tw, wT);

    k_fusem<<<gs, 256, 0, stream>>>(imgT, gdT, wT + (size_t)7 * 36864, tb, ajbf, bufA);

    // kg chain: two fused double-convs
    k_conv2x<0><<<gs, 256, 0, stream>>>(bufA, wT + (size_t)0 * 36864, wT + (size_t)1 * 36864,
                                        kb1, kb2, akg, nullptr, bufB);
    k_conv2x<0><<<gs, 256, 0, stream>>>(bufB, wT + (size_t)2 * 36864, wT + (size_t)3 * 36864,
                                        kb3, kb4, akg, nullptr, bufA);

    k_jbfm<<<gw, 256, 0, stream>>>(bufA, img, wT + (size_t)6 * 36864, kb5, bufC);

    // jbf chain: fused conv+PReLU+conv+residual, NCHW fp32 out
    k_conv2x<2><<<gs, 256, 0, stream>>>(bufC, wT + (size_t)4 * 36864, wT + (size_t)5 * 36864,
                                        jb1, jb2, ajbf, img, out);
}

// Round 8
// 288.935 us; speedup vs baseline: 2.6393x; 1.0490x over previous
//
#include <hip/hip_runtime.h>

#define HW 65536

typedef __bf16 bf16x8 __attribute__((ext_vector_type(8)));
typedef float f32x16 __attribute__((ext_vector_type(16)));

__device__ inline unsigned short f2bf(float x) {
    union { float f; unsigned u; } v; v.f = x;
    unsigned r = v.u + 0x7FFF + ((v.u >> 16) & 1);   // RNE
    return (unsigned short)(r >> 16);
}
__device__ inline float bfhi2f(unsigned u) {        // high 16 bits as f32
    union { unsigned u; float f; } v; v.u = u & 0xffff0000u; return v.f;
}
__device__ inline float bflo2f(unsigned u) {        // low 16 bits as f32
    union { unsigned u; float f; } v; v.u = u << 16; return v.f;
}

union FragU { uint4 u; bf16x8 v; };
__device__ inline bf16x8 ld_frag(const uint4* p) { FragU t; t.u = *p; return t.v; }

// XCD-slab swizzle: XCD = lin & 7 (dispatch round-robin). Slab s owns a
// contiguous 64-row band of one batch: b = s>>2, rows [(s&3)*64, +64).

// ---------------------------------------------------------------------------
// k_pre: merged k_tr (y<4) + k_wprep (y>=4). One dispatch instead of two.
// tr: NCHW fp32 -> NHWC bf16 (64-px x 64-ch tiles).
// wprep y2<6: 3x3 conv weights -> frag-linear [(tap*8+igg)*64+oc]*8+j
//       y2==6: kg_w5 combine layout;  y2==7: 1x1 weights [kg*64+oc]*8+j
// ---------------------------------------------------------------------------
__global__ __launch_bounds__(256) void k_pre(
    const float* __restrict__ img, const float* __restrict__ gd,
    const float* __restrict__ w0, const float* __restrict__ w1,
    const float* __restrict__ w2, const float* __restrict__ w3,
    const float* __restrict__ w4, const float* __restrict__ w5,
    const float* __restrict__ w5c, const float* __restrict__ tw,
    unsigned short* __restrict__ imgT, unsigned short* __restrict__ gdT,
    unsigned short* __restrict__ wT)
{
    __shared__ float sT[64 * 66];
    int tid = threadIdx.x;
    int y = blockIdx.y;
    if (y < 4) {
        int z = y;                  // tensor*2 + b
        int b = z & 1;
        const float* src = (z >> 1) ? gd : img;
        unsigned short* dst = (z >> 1) ? gdT : imgT;
        int px0 = blockIdx.x * 64;
        size_t sbase = (size_t)b * 64 * HW + px0;

#pragma unroll
        for (int i = 0; i < 4; ++i) {
            int e = i * 256 + tid;
            int ic = e >> 4, seg = e & 15;
            float4 v = *(const float4*)(src + sbase + (size_t)ic * HW + seg * 4);
            float* p = &sT[ic * 66 + seg * 4];
            ((float2*)p)[0] = make_float2(v.x, v.y);
            ((float2*)p)[1] = make_float2(v.z, v.w);
        }
        __syncthreads();

        size_t dbase = (size_t)b * HW * 64 + (size_t)px0 * 64;
#pragma unroll
        for (int k = 0; k < 2; ++k) {
            int idx = k * 256 + tid;
            int px = idx >> 3, u = idx & 7;
            union { uint4 q; unsigned short h[8]; } o;
#pragma unroll
            for (int j = 0; j < 8; ++j)
                o.h[j] = f2bf(sT[(u * 8 + j) * 66 + px]);
            *(uint4*)(dst + dbase + (size_t)px * 64 + u * 8) = o.q;
        }
    } else {
        int y2 = y - 4;
        unsigned short* o = wT + (size_t)y2 * 36864;
        int e = blockIdx.x * 256 + tid;      // stride covers range in one pass
        if (y2 < 6) {
            const float* ws_[6] = {w0, w1, w2, w3, w4, w5};
            const float* w = ws_[y2];
            if (e < 36864) {
                int tap = e >> 12, oc = (e >> 6) & 63, ic = e & 63;
                int igg = ic >> 3, j = ic & 7;
                int dst = ((tap * 8 + igg) * 64 + oc) * 8 + j;
                o[dst] = f2bf(w[(oc * 64 + ic) * 9 + tap]);
            }
        } else if (y2 == 6) {
            if (e < 36864) o[e] = f2bf(w5c[e]);
        } else {
            if (e < 8192) {
                int oc = e >> 7, ic = e & 127;
                int kg = ic >> 3, j = ic & 7;
                o[((kg * 64 + oc) << 3) + j] = f2bf(tw[e]);
            }
        }
    }
}

// ---------------------------------------------------------------------------
// k_fuse3: FUSED 1x1(2C->C)+PReLU(a_jbf) + 3x3+PReLU(a_kg) + 3x3+PReLU(a_kg).
// 16x8 output tile, XCD-slab swizzled, oc-split waves (w2,g).
// Stage img/gd NHWC halo (12x20 cells) in 4 tensor-half phases (dbuf,
// reg-prefetch) -> 1x1 on 240 cells -> sC0 (swizzled, OOB zeroed) ->
// conv1 on 18x10 -> sC1 -> conv2 16x8 -> NHWC bf16 out.
// LDS 54.5KB -> 2 blocks/CU.
// ---------------------------------------------------------------------------
__global__ __launch_bounds__(256, 2) void k_fuse3(
    const unsigned short* __restrict__ imgT, const unsigned short* __restrict__ gdT,
    const unsigned short* __restrict__ wTf,
    const unsigned short* __restrict__ w1T, const unsigned short* __restrict__ w2T,
    const float* __restrict__ tb, const float* __restrict__ b1,
    const float* __restrict__ b2, const float* __restrict__ ajbf,
    const float* __restrict__ akg, unsigned short* __restrict__ out)
{
    __shared__ __align__(16) char smem[54528];
    // sS dbuf: 2 x 1200 uint4 ([cell*5+ig], stride-20-word conflict-free) @0/19200
    // sC0 overlay @0: 240 cells x 8 uint4 (swizzled) = 30720
    // sC1 @30720: 180 cells x 8 uint4 = 23040  (-> 53760)
    // sB @53760: [0..63]=tb [64..127]=b1 [128..191]=b2
    // sT16 overlay @0: 16KB epilogue
    float* sB = (float*)(smem + 53760);
    uint4* sS0 = (uint4*)smem;
    uint4* sS1 = (uint4*)(smem + 19200);

    int tid = threadIdx.x;
    int wv = tid >> 6, lane = tid & 63;
    int half = lane >> 5, l31 = lane & 31;
    int w2 = wv >> 1, g = wv & 1;
    int lin = blockIdx.x + (blockIdx.y << 4) + (blockIdx.z << 9);  // [0,1024)
    int slab = lin & 7, sub = lin >> 3;
    int b = slab >> 2;
    int y0 = (slab & 3) * 64 + (sub >> 4) * 8;
    int x0 = (sub & 15) * 16;
    const size_t zbase = (size_t)b * HW * 64;
    const uint4* wgf = (const uint4*)wTf;          // [kg*64+oc]
    const uint4* wg1 = (const uint4*)w1T;          // [(tap*8+igg)*64+oc]
    const uint4* wg2 = (const uint4*)w2T;

    if (tid < 64) sB[tid] = tb[tid];
    else if (tid < 128) sB[tid] = b1[tid - 64];
    else if (tid < 192) sB[tid] = b2[tid - 128];

    // staging: 240 cells (12x20 halo, origin y0-2,x0-2) x 4 ig of one 32ch half
    auto loadS = [&](int t, int h, uint4* rx) {
        const unsigned short* src = t ? gdT : imgT;
#pragma unroll
        for (int i = 0; i < 4; ++i) {
            int e = i * 256 + tid;               // active < 960
            int cell = e >> 2, ig = e & 3;
            int r = cell / 20, c2 = cell - r * 20;
            int gy = y0 - 2 + r, gx = x0 - 2 + c2;
            rx[i] = make_uint4(0, 0, 0, 0);
            if (e < 960 && gy >= 0 && gy < 256 && gx >= 0 && gx < 256)
                rx[i] = *(const uint4*)(src + zbase + ((size_t)(gy * 256 + gx)) * 64 + h * 32 + ig * 8);
        }
    };
    auto writeS = [&](uint4* s, const uint4* rx) {
#pragma unroll
        for (int i = 0; i < 4; ++i) {
            int e = i * 256 + tid;
            if (e < 960) s[(e >> 2) * 5 + (e & 3)] = rx[i];
        }
    };

    // 1x1: this wave's cells (4 slots of 32)
    int cell0[4];
#pragma unroll
    for (int s = 0; s < 4; ++s) {
        int c = g * 128 + s * 32 + l31;
        cell0[s] = c < 240 ? c : 239;
    }
    f32x16 acc0[4];
#pragma unroll
    for (int s = 0; s < 4; ++s)
#pragma unroll
        for (int r = 0; r < 16; ++r) acc0[s][r] = 0.f;

    auto mm1 = [&](int t, int h, const uint4* sS) {
#pragma unroll
        for (int c = 0; c < 2; ++c) {
            int ig = c * 2 + half;
            int kg = t * 8 + h * 4 + ig;
            bf16x8 af = ld_frag(&wgf[kg * 64 + w2 * 32 + l31]);
#pragma unroll
            for (int s = 0; s < 4; ++s) {
                bf16x8 bb = ld_frag(&sS[cell0[s] * 5 + ig]);
                acc0[s] = __builtin_amdgcn_mfma_f32_32x32x16_bf16(af, bb, acc0[s], 0, 0, 0);
            }
        }
    };

    uint4 rx[4];
    loadS(0, 0, rx);
    writeS(sS0, rx);
    loadS(0, 1, rx);            // prefetch p1
    __syncthreads();            // sS0(p0) ready
    mm1(0, 0, sS0);
    writeS(sS1, rx);
    loadS(1, 0, rx);            // prefetch p2
    __syncthreads();            // sS1(p1) ready; all waves past mm1(p0)
    mm1(0, 1, sS1);
    writeS(sS0, rx);
    loadS(1, 1, rx);            // prefetch p3
    __syncthreads();            // sS0(p2) ready; all waves past mm1(p1)
    mm1(1, 0, sS0);
    writeS(sS1, rx);
    __syncthreads();            // sS1(p3) ready; all waves past mm1(p2)
    mm1(1, 1, sS1);

    // epi0: tb + PReLU(ajbf), OOB zero, pack bf16 -> sC0 (overlays sS)
    float s_jbf = ajbf[0], s_kg = akg[0];
    __syncthreads();            // all 1x1 reads done
    unsigned short* sC0 = (unsigned short*)smem;
#pragma unroll
    for (int s = 0; s < 4; ++s) {
        int cell = g * 128 + s * 32 + l31;
        if (cell < 240) {
            int R = cell / 20, C = cell - R * 20;
            int gy = y0 - 2 + R, gx = x0 - 2 + C;
            bool inb = (gy >= 0 && gy < 256 && gx >= 0 && gx < 256);
#pragma unroll
            for (int q2 = 0; q2 < 4; ++q2) {
                unsigned short hw[4];
#pragma unroll
                for (int j = 0; j < 4; ++j) {
                    int r = (q2 << 2) | j;
                    int oc = w2 * 32 + j + 8 * q2 + 4 * half;
                    float v = acc0[s][r] + sB[oc];
                    v = (v >= 0.f) ? v : s_jbf * v;
                    if (!inb) v = 0.f;
                    hw[j] = f2bf(v);
                }
                int up = (w2 * 4 + q2) ^ (cell & 7);
                *(uint2*)&sC0[cell * 64 + up * 8 + half * 4] =
                    make_uint2((unsigned)hw[0] | ((unsigned)hw[1] << 16),
                               (unsigned)hw[2] | ((unsigned)hw[3] << 16));
            }
        }
    }
    __syncthreads();            // sC0 ready

    // conv1: 18x10 output-halo grid from sC0
    int cellv[3], ibv[3];
#pragma unroll
    for (int s = 0; s < 3; ++s) {
        int c = g * 96 + s * 32 + l31;
        cellv[s] = c;
        int cc = c < 180 ? c : 179;
        ibv[s] = (cc / 18) * 20 + (cc % 18);
    }
    f32x16 acc1[3];
#pragma unroll
    for (int s = 0; s < 3; ++s)
#pragma unroll
        for (int r = 0; r < 16; ++r) acc1[s][r] = 0.f;

    {
        const uint4* sC04 = (const uint4*)smem;
#pragma unroll
        for (int dy = 0; dy < 3; ++dy) {
#pragma unroll
            for (int dx = 0; dx < 3; ++dx) {
                int tap = dy * 3 + dx;
                int doff = dy * 20 + dx;
#pragma unroll
                for (int c4 = 0; c4 < 4; ++c4) {
                    int unit = c4 * 2 + half;
                    bf16x8 af = ld_frag(&wg1[(tap * 8 + unit) * 64 + w2 * 32 + l31]);
#pragma unroll
                    for (int s = 0; s < 3; ++s) {
                        int cc = ibv[s] + doff;
                        bf16x8 bb = ld_frag(&sC04[cc * 8 + (unit ^ (cc & 7))]);
                        acc1[s] = __builtin_amdgcn_mfma_f32_32x32x16_bf16(af, bb, acc1[s], 0, 0, 0);
                    }
                }
            }
        }
    }

    // epi1: b1 + PReLU(akg), OOB zero, pack -> sC1 (disjoint region, no bar)
    unsigned short* sC1 = (unsigned short*)(smem + 30720);
#pragma unroll
    for (int s = 0; s < 3; ++s) {
        int cell = cellv[s];
        if (cell < 180) {
            int orow = cell / 18, ocol = cell - orow * 18;
            int gy = y0 - 1 + orow, gx = x0 - 1 + ocol;
            bool inb = (gy >= 0 && gy < 256 && gx >= 0 && gx < 256);
#pragma unroll
            for (int q2 = 0; q2 < 4; ++q2) {
                unsigned short hw[4];
#pragma unroll
                for (int j = 0; j < 4; ++j) {
                    int r = (q2 << 2) | j;
                    int oc = w2 * 32 + j + 8 * q2 + 4 * half;
                    float v = acc1[s][r] + sB[64 + oc];
                    v = (v >= 0.f) ? v : s_kg * v;
                    if (!inb) v = 0.f;
                    hw[j] = f2bf(v);
                }
                int up = (w2 * 4 + q2) ^ (cell & 7);
                *(uint2*)&sC1[cell * 64 + up * 8 + half * 4] =
                    make_uint2((unsigned)hw[0] | ((unsigned)hw[1] << 16),
                               (unsigned)hw[2] | ((unsigned)hw[3] << 16));
            }
        }
    }
    __syncthreads();            // sC1 ready

    // conv2: 16x8 output tile from sC1
    f32x16 acc2[2];
#pragma unroll
    for (int s = 0; s < 2; ++s)
#pragma unroll
        for (int r = 0; r < 16; ++r) acc2[s][r] = 0.f;

    int rowS[2], colS[2];
#pragma unroll
    for (int s = 0; s < 2; ++s) {
        int px = g * 64 + s * 32 + l31;
        rowS[s] = px >> 4; colS[s] = px & 15;
    }
    {
        const uint4* sC14 = (const uint4*)(smem + 30720);
#pragma unroll
        for (int dy = 0; dy < 3; ++dy) {
#pragma unroll
            for (int dx = 0; dx < 3; ++dx) {
                int tap = dy * 3 + dx;
#pragma unroll
                for (int c = 0; c < 4; ++c) {
                    int ig = c * 2 + half;
                    bf16x8 af = ld_frag(&wg2[(tap * 8 + ig) * 64 + w2 * 32 + l31]);
#pragma unroll
                    for (int s = 0; s < 2; ++s) {
                        int cl = (rowS[s] + dy) * 18 + colS[s] + dx;
                        bf16x8 bb = ld_frag(&sC14[cl * 8 + (ig ^ (cl & 7))]);
                        acc2[s] = __builtin_amdgcn_mfma_f32_32x32x16_bf16(af, bb, acc2[s], 0, 0, 0);
                    }
                }
            }
        }
    }

    // epilogue: b2 + PReLU(akg) -> sT16 (overlays dead sC0) -> NHWC bf16 out
    unsigned short* sT16 = (unsigned short*)smem;
#pragma unroll
    for (int s = 0; s < 2; ++s) {
        int px = g * 64 + s * 32 + l31;
#pragma unroll
        for (int q2 = 0; q2 < 4; ++q2) {
            unsigned short hw[4];
#pragma unroll
            for (int j = 0; j < 4; ++j) {
                int r = (q2 << 2) | j;
                int oc = w2 * 32 + j + 8 * q2 + 4 * half;
                float v = acc2[s][r] + sB[128 + oc];
                v = (v >= 0.f) ? v : s_kg * v;
                hw[j] = f2bf(v);
            }
            int up = (w2 * 4 + q2) ^ (px & 7);
            uint2* p = (uint2*)&sT16[px * 64 + up * 8 + half * 4];
            *p = make_uint2((unsigned)hw[0] | ((unsigned)hw[1] << 16),
                            (unsigned)hw[2] | ((unsigned)hw[3] << 16));
        }
    }
    __syncthreads();
#pragma unroll
    for (int k = 0; k < 4; ++k) {
        int idx = k * 256 + tid;
        int row = idx >> 7, rem = idx & 127;
        int col = rem >> 3, u = rem & 7;
        int px = row * 16 + col;
        uint4 v = *(uint4*)&sT16[px * 64 + (u ^ (px & 7)) * 8];
        *(uint4*)(out + zbase + ((size_t)((y0 + row) * 256 + x0 + col)) * 64 + u * 8) = v;
    }
}

// ---------------------------------------------------------------------------
// k_conv2x: FUSED pair of 3x3 convs (round-7, unchanged).
// ---------------------------------------------------------------------------
#define XU 5

template<int MODE>
__global__ __launch_bounds__(256, 4) void k_conv2x(
    const unsigned short* __restrict__ in,
    const unsigned short* __restrict__ w1T, const unsigned short* __restrict__ w2T,
    const float* __restrict__ b1, const float* __restrict__ b2,
    const float* __restrict__ a, const float* __restrict__ res,
    void* __restrict__ outv)
{
    __shared__ __align__(16) char smem[38912];
    uint4* sIn0 = (uint4*)smem;
    uint4* sIn1 = (uint4*)(smem + 19200);
    float* sB = (float*)(smem + 38400);

    int tid = threadIdx.x;
    int wv = tid >> 6, lane = tid & 63;
    int half = lane >> 5, l31 = lane & 31;
    int w2 = wv >> 1, g = wv & 1;
    int lin = blockIdx.x + (blockIdx.y << 4) + (blockIdx.z << 9);
    int slab = lin & 7, sub = lin >> 3;
    int b = slab >> 2;
    int y0 = (slab & 3) * 64 + (sub >> 4) * 8;
    int x0 = (sub & 15) * 16;
    const size_t zbase = (size_t)b * HW * 64;
    const uint4* wg1 = (const uint4*)w1T;
    const uint4* wg2 = (const uint4*)w2T;

    if (tid < 64) sB[tid] = b1[tid];
    else if (tid < 128) sB[tid] = b2[tid - 64];

    auto loadIn = [&](int h, uint4* rx) {
#pragma unroll
        for (int i = 0; i < 4; ++i) {
            int e = i * 256 + tid;
            int cell = e >> 2, ig = e & 3;
            int r = cell / 20, c2 = cell - r * 20;
            int gy = y0 - 2 + r, gx = x0 - 2 + c2;
            rx[i] = make_uint4(0, 0, 0, 0);
            bool act = (i < 3) || (e < 960);
            if (act && gy >= 0 && gy < 256 && gx >= 0 && gx < 256)
                rx[i] = *(const uint4*)(in + zbase + ((size_t)(gy * 256 + gx)) * 64 + h * 32 + ig * 8);
        }
    };
    auto writeIn = [&](uint4* s, const uint4* rx) {
#pragma unroll
        for (int i = 0; i < 4; ++i) {
            int e = i * 256 + tid;
            if (i < 3 || e < 960) s[(e >> 2) * XU + (e & 3)] = rx[i];
        }
    };

    int cellv[3], ibv[3];
#pragma unroll
    for (int s = 0; s < 3; ++s) {
        int c = g * 96 + s * 32 + l31;
        cellv[s] = c;
        int cc = c < 180 ? c : 179;
        ibv[s] = (cc / 18) * 20 + (cc % 18);
    }

    f32x16 acc1[3];
#pragma unroll
    for (int s = 0; s < 3; ++s)
#pragma unroll
        for (int r = 0; r < 16; ++r) acc1[s][r] = 0.f;

    auto conv1_h = [&](int h, const uint4* sInp) {
#pragma unroll
        for (int dy = 0; dy < 3; ++dy) {
#pragma unroll
            for (int dx = 0; dx < 3; ++dx) {
                int tap = dy * 3 + dx;
                int doff = dy * 20 + dx;
#pragma unroll
                for (int c = 0; c < 2; ++c) {
                    int ig = c * 2 + half;
                    bf16x8 af = ld_frag(&wg1[(tap * 8 + h * 4 + ig) * 64 + w2 * 32 + l31]);
#pragma unroll
                    for (int s = 0; s < 3; ++s) {
                        bf16x8 bb = ld_frag(&sInp[(ibv[s] + doff) * XU + ig]);
                        acc1[s] = __builtin_amdgcn_mfma_f32_32x32x16_bf16(af, bb, acc1[s], 0, 0, 0);
                    }
                }
            }
        }
    };

    uint4 rx[4];
    loadIn(0, rx);
    writeIn(sIn0, rx);
    uint4 ry[4];
    loadIn(1, ry);
    __syncthreads();
    conv1_h(0, sIn0);
    writeIn(sIn1, ry);
    __syncthreads();
    conv1_h(1, sIn1);

    float s1 = a[0];
    __syncthreads();
    unsigned short* sC16 = (unsigned short*)smem;
#pragma unroll
    for (int s = 0; s < 3; ++s) {
        int cell = cellv[s];
        if (cell < 180) {
            int orow = cell / 18, ocol = cell - orow * 18;
            int gy = y0 - 1 + orow, gx = x0 - 1 + ocol;
            bool inb = (gy >= 0 && gy < 256 && gx >= 0 && gx < 256);
#pragma unroll
            for (int q2 = 0; q2 < 4; ++q2) {
                unsigned short hw[4];
#pragma unroll
                for (int j = 0; j < 4; ++j) {
                    int r = (q2 << 2) | j;
                    int oc = w2 * 32 + j + 8 * q2 + 4 * half;
                    float v = acc1[s][r] + sB[oc];
                    v = (v >= 0.f) ? v : s1 * v;
                    if (!inb) v = 0.f;
                    hw[j] = f2bf(v);
                }
                int up = (w2 * 4 + q2) ^ (cell & 7);
                *(uint2*)&sC16[cell * 64 + up * 8 + half * 4] =
                    make_uint2((unsigned)hw[0] | ((unsigned)hw[1] << 16),
                               (unsigned)hw[2] | ((unsigned)hw[3] << 16));
            }
        }
    }
    __syncthreads();

    f32x16 acc2[2];
#pragma unroll
    for (int s = 0; s < 2; ++s)
#pragma unroll
        for (int r = 0; r < 16; ++r) acc2[s][r] = 0.f;

    int rowS[2], colS[2];
#pragma unroll
    for (int s = 0; s < 2; ++s) {
        int px = g * 64 + s * 32 + l31;
        rowS[s] = px >> 4; colS[s] = px & 15;
    }
    {
        const uint4* sC4 = (const uint4*)smem;
#pragma unroll
        for (int dy = 0; dy < 3; ++dy) {
#pragma unroll
            for (int dx = 0; dx < 3; ++dx) {
                int tap = dy * 3 + dx;
#pragma unroll
                for (int c = 0; c < 4; ++c) {
                    int ig = c * 2 + half;
                    bf16x8 af = ld_frag(&wg2[(tap * 8 + ig) * 64 + w2 * 32 + l31]);
#pragma unroll
                    for (int s = 0; s < 2; ++s) {
                        int cl = (rowS[s] + dy) * 18 + colS[s] + dx;
                        bf16x8 bb = ld_frag(&sC4[cl * 8 + (ig ^ (cl & 7))]);
                        acc2[s] = __builtin_amdgcn_mfma_f32_32x32x16_bf16(af, bb, acc2[s], 0, 0, 0);
                    }
                }
            }
        }
    }

    if (MODE == 0) {
        __syncthreads();
        unsigned short* sT16 = (unsigned short*)smem;
#pragma unroll
        for (int s = 0; s < 2; ++s) {
            int px = g * 64 + s * 32 + l31;
#pragma unroll
            for (int q2 = 0; q2 < 4; ++q2) {
                unsigned short hw[4];
#pragma unroll
                for (int j = 0; j < 4; ++j) {
                    int r = (q2 << 2) | j;
                    int oc = w2 * 32 + j + 8 * q2 + 4 * half;
                    float v = acc2[s][r] + sB[64 + oc];
                    v = (v >= 0.f) ? v : s1 * v;
                    hw[j] = f2bf(v);
                }
                int up = (w2 * 4 + q2) ^ (px & 7);
                uint2* p = (uint2*)&sT16[px * 64 + up * 8 + half * 4];
                *p = make_uint2((unsigned)hw[0] | ((unsigned)hw[1] << 16),
                                (unsigned)hw[2] | ((unsigned)hw[3] << 16));
            }
        }
        __syncthreads();
        unsigned short* outT = (unsigned short*)outv;
#pragma unroll
        for (int k = 0; k < 4; ++k) {
            int idx = k * 256 + tid;
            int row = idx >> 7, rem = idx & 127;
            int col = rem >> 3, u = rem & 7;
            int px = row * 16 + col;
            uint4 v = *(uint4*)&sT16[px * 64 + (u ^ (px & 7)) * 8];
            *(uint4*)(outT + zbase + ((size_t)((y0 + row) * 256 + x0 + col)) * 64 + u * 8) = v;
        }
    } else {
        float* outF = (float*)outv;
#pragma unroll
        for (int s = 0; s < 2; ++s) {
            int px = g * 64 + s * 32 + l31;
            int y = y0 + (px >> 4), x = x0 + (px & 15);
            size_t pbase = (size_t)b * 64 * HW + (size_t)y * 256 + x;
#pragma unroll
            for (int r = 0; r < 16; ++r) {
                int oc = w2 * 32 + (r & 3) + 8 * (r >> 2) + 4 * half;
                float v = acc2[s][r] + sB[64 + oc];
                v += res[pbase + (size_t)oc * HW];
                outF[pbase + (size_t)oc * HW] = v;
            }
        }
    }
}

// ---------------------------------------------------------------------------
// k_jbfm: fused kg_w5 (C->576) + dynamic-kernel combine (round-7, unchanged).
// ---------------------------------------------------------------------------
struct OffTab { unsigned v[9][32]; int chlo[9]; };
constexpr OffTab make_tab() {
    OffTab t{};
    for (int kk = 0; kk < 9; ++kk) {
        int chlo = (kk * 64) / 9;
        t.chlo[kk] = chlo;
        for (int ot = 0; ot < 2; ++ot)
            for (int r = 0; r < 16; ++r) {
                int cc0 = ot * 32 + (r & 3) + 8 * (r >> 2);
                int q0 = kk * 64 + cc0, q1 = q0 + 4;
                int o0 = (q0 / 9 - chlo) * 360 + (q0 % 9 / 3) * 40 + (q0 % 9 % 3);
                int o1 = (q1 / 9 - chlo) * 360 + (q1 % 9 / 3) * 40 + (q1 % 9 % 3);
                t.v[kk][ot * 16 + r] = (unsigned)o0 | ((unsigned)o1 << 16);
            }
    }
    return t;
}
__constant__ OffTab kOff = make_tab();

__global__ __launch_bounds__(256, 2) void k_jbfm(
    const unsigned short* __restrict__ y4, const float* __restrict__ img,
    const unsigned short* __restrict__ w5T, const float* __restrict__ b5,
    unsigned short* __restrict__ out)
{
    __shared__ __align__(16) char smem[78592];
    uint4* sY = (uint4*)smem;
    float* sB5 = (float*)(smem + 76288);
    unsigned short* sT16 = (unsigned short*)smem;

    int tid = threadIdx.x;
    int wv = tid >> 6, lane = tid & 63;
    int half = lane >> 5, l31 = lane & 31;
    int lin = blockIdx.x + (blockIdx.y << 3) + (blockIdx.z << 8);
    int slab = lin & 7, sub = lin >> 3;
    int b = slab >> 2;
    int y0 = (slab & 3) * 64 + (sub >> 3) * 8;
    int x0 = (sub & 7) * 32;
    size_t zbase = (size_t)b * HW * 64;
    size_t ibase = (size_t)b * 64 * HW;

    int p_off[3], p_dst[3];
    bool p_a[3], p_b[3], p_act[3];
#pragma unroll
    for (int i = 0; i < 3; ++i) {
        int e = i * 256 + tid;
        bool act = e < 720;
        int ch = e / 90, rem = e - ch * 90;
        int rp = rem / 10, seg = rem - rp * 10;
        int gy = y0 + rp - 1;
        int gxb = x0 - 4 + seg * 4;
        bool xok = (gxb >= 0 && gxb < 256);
        p_act[i] = act;
        p_a[i] = act && xok && gy >= 0 && gy < 256;
        p_b[i] = act && xok && (gy + 1) < 256;
        p_off[i] = ch * HW + gy * 256 + gxb;
        p_dst[i] = ch * 360 + rp * 40 + seg * 4;
    }

#pragma unroll
    for (int i = 0; i < 8; ++i) {
        int e = i * 256 + tid;
        int px = e >> 3, ig = e & 7;
        int gy = y0 + (px >> 5), gx = x0 + (px & 31);
        sY[px * 9 + ig] = *(const uint4*)(y4 + zbase + ((size_t)(gy * 256 + gx)) * 64 + ig * 8);
    }
    for (int e = tid; e < 576; e += 256) sB5[e] = b5[e];

    {
        uint4* sW50 = (uint4*)(smem + 36864);
        unsigned* sP0 = (unsigned*)(smem + 53248);
#pragma unroll
        for (int u = 0; u < 2; ++u) {
            int uu = u * 256 + tid;
            int cc = uu & 63, ig = uu >> 6;
            sW50[uu] = ((const uint4*)w5T)[cc * 8 + ig];
        }
        const float* rp0 = img + ibase;
#pragma unroll
        for (int i = 0; i < 3; ++i) {
            float4 fa = make_float4(0, 0, 0, 0), fb = make_float4(0, 0, 0, 0);
            if (p_a[i]) fa = *(const float4*)(rp0 + p_off[i]);
            if (p_b[i]) fb = *(const float4*)(rp0 + p_off[i] + 256);
            if (p_act[i]) {
                uint4 pk;
                pk.x = (unsigned)f2bf(fa.x) | ((unsigned)f2bf(fb.x) << 16);
                pk.y = (unsigned)f2bf(fa.y) | ((unsigned)f2bf(fb.y) << 16);
                pk.z = (unsigned)f2bf(fa.z) | ((unsigned)f2bf(fb.z) << 16);
                pk.w = (unsigned)f2bf(fa.w) | ((unsigned)f2bf(fb.w) << 16);
                *(uint4*)&sP0[p_dst[i]] = pk;
            }
        }
    }

    float jb[2][2][16];
#pragma unroll
    for (int i = 0; i < 2; ++i)
#pragma unroll
        for (int j = 0; j < 2; ++j)
#pragma unroll
            for (int r = 0; r < 16; ++r) jb[i][j][r] = 0.f;

    __syncthreads();

#pragma unroll 1
    for (int kk = 0; kk < 9; ++kk) {
        const int cur = kk & 1;
        const uint4* sW5c = (const uint4*)(smem + 36864 + cur * 8192);
        const unsigned* sPc = (const unsigned*)(smem + 53248 + cur * 11520);

        uint4 wpre0, wpre1;
        float4 pfa[3], pfb[3];
        if (kk < 8) {
            const int nk = kk + 1;
            const int chlo_n = kOff.chlo[nk];
            {
                int cc = tid & 63, ig = tid >> 6;
                wpre0 = ((const uint4*)w5T)[(nk * 64 + cc) * 8 + ig];
                int uu = 256 + tid;
                int cc1 = uu & 63, ig1 = uu >> 6;
                wpre1 = ((const uint4*)w5T)[(nk * 64 + cc1) * 8 + ig1];
            }
            const float* rp0 = img + ibase + (size_t)chlo_n * HW;
#pragma unroll
            for (int i = 0; i < 3; ++i) {
                pfa[i] = make_float4(0, 0, 0, 0);
                pfb[i] = make_float4(0, 0, 0, 0);
                if (p_a[i]) pfa[i] = *(const float4*)(rp0 + p_off[i]);
                if (p_b[i]) pfb[i] = *(const float4*)(rp0 + p_off[i] + 256);
            }
        }

        f32x16 acc[2][2];
#pragma unroll
        for (int ot = 0; ot < 2; ++ot)
#pragma unroll
            for (int r = 0; r < 16; ++r) {
                int cc0 = ot * 32 + (r & 3) + 8 * (r >> 2);
                float bv = sB5[kk * 64 + cc0 + 4 * half];
                acc[ot][0][r] = bv;
                acc[ot][1][r] = bv;
            }

#pragma unroll
        for (int c = 0; c < 4; ++c) {
            int ig = c * 2 + half;
            bf16x8 a0 = ld_frag(&sW5c[ig * 64 + l31]);
            bf16x8 a1 = ld_frag(&sW5c[ig * 64 + 32 + l31]);
            int p0 = wv * 64 + l31;
            bf16x8 b0 = ld_frag(&sY[p0 * 9 + ig]);
            bf16x8 b1 = ld_frag(&sY[(p0 + 32) * 9 + ig]);
            acc[0][0] = __builtin_amdgcn_mfma_f32_32x32x16_bf16(a0, b0, acc[0][0], 0, 0, 0);
            acc[0][1] = __builtin_amdgcn_mfma_f32_32x32x16_bf16(a0, b1, acc[0][1], 0, 0, 0);
            acc[1][0] = __builtin_amdgcn_mfma_f32_32x32x16_bf16(a1, b0, acc[1][0], 0, 0, 0);
            acc[1][1] = __builtin_amdgcn_mfma_f32_32x32x16_bf16(a1, b1, acc[1][1], 0, 0, 0);
        }

        {
            const unsigned* basep = sPc + wv * 80 + l31 + 3;
            const unsigned* tab = kOff.v[kk];
#pragma unroll
            for (int ot = 0; ot < 2; ++ot)
#pragma unroll
                for (int r = 0; r < 16; ++r) {
                    unsigned oo = tab[ot * 16 + r];
                    unsigned o0 = oo & 0xffffu, o1 = oo >> 16;
                    unsigned pv = basep[half ? o1 : o0];
                    jb[ot][0][r] = fmaf(acc[ot][0][r], bflo2f(pv), jb[ot][0][r]);
                    jb[ot][1][r] = fmaf(acc[ot][1][r], bfhi2f(pv), jb[ot][1][r]);
                }
        }

        if (kk < 8) {
            uint4* sW5n = (uint4*)(smem + 36864 + (cur ^ 1) * 8192);
            unsigned* sPn = (unsigned*)(smem + 53248 + (cur ^ 1) * 11520);
            sW5n[tid] = wpre0;
            sW5n[256 + tid] = wpre1;
#pragma unroll
            for (int i = 0; i < 3; ++i) {
                if (p_act[i]) {
                    uint4 pk;
                    pk.x = (unsigned)f2bf(pfa[i].x) | ((unsigned)f2bf(pfb[i].x) << 16);
                    pk.y = (unsigned)f2bf(pfa[i].y) | ((unsigned)f2bf(pfb[i].y) << 16);
                    pk.z = (unsigned)f2bf(pfa[i].z) | ((unsigned)f2bf(pfb[i].z) << 16);
                    pk.w = (unsigned)f2bf(pfa[i].w) | ((unsigned)f2bf(pfb[i].w) << 16);
                    *(uint4*)&sPn[p_dst[i]] = pk;
                }
            }
        }
        __syncthreads();
    }

#pragma unroll
    for (int ot = 0; ot < 2; ++ot)
#pragma unroll
        for (int pt = 0; pt < 2; ++pt) {
            int px = wv * 64 + pt * 32 + l31;
#pragma unroll
            for (int q2 = 0; q2 < 4; ++q2) {
                unsigned short hw[4];
#pragma unroll
                for (int j = 0; j < 4; ++j) {
                    int r = (q2 << 2) | j;
                    hw[j] = f2bf(jb[ot][pt][r]);
                }
                int unit = ot * 4 + q2;
                int up = unit ^ (px & 7);
                uint2* p = (uint2*)&sT16[px * 64 + up * 8 + half * 4];
                *p = make_uint2((unsigned)hw[0] | ((unsigned)hw[1] << 16),
                                (unsigned)hw[2] | ((unsigned)hw[3] << 16));
            }
        }
    __syncthreads();
#pragma unroll
    for (int k = 0; k < 8; ++k) {
        int col = tid >> 3, u = tid & 7;
        int px = k * 32 + col;
        uint4 v = *(uint4*)&sT16[px * 64 + (u ^ (px & 7)) * 8];
        *(uint4*)(out + zbase + ((size_t)((y0 + k) * 256 + x0 + col)) * 64 + u * 8) = v;
    }
}

// ---------------------------------------------------------------------------
extern "C" void kernel_launch(void* const* d_in, const int* in_sizes, int n_in,
                              void* d_out, int out_size, void* d_ws, size_t ws_size,
                              hipStream_t stream) {
    const float* img  = (const float*)d_in[0];
    const float* gd   = (const float*)d_in[1];
    const float* tw   = (const float*)d_in[2];
    const float* tb   = (const float*)d_in[3];
    const float* ajbf = (const float*)d_in[4];
    const float* kw1  = (const float*)d_in[5];
    const float* kb1  = (const float*)d_in[6];
    const float* kw2  = (const float*)d_in[7];
    const float* kb2  = (const float*)d_in[8];
    const float* kw3  = (const float*)d_in[9];
    const float* kb3  = (const float*)d_in[10];
    const float* kw4  = (const float*)d_in[11];
    const float* kb4  = (const float*)d_in[12];
    const float* kw5  = (const float*)d_in[13];
    const float* kb5  = (const float*)d_in[14];
    const float* akg  = (const float*)d_in[15];
    const float* jw1  = (const float*)d_in[16];
    const float* jb1  = (const float*)d_in[17];
    const float* jw2  = (const float*)d_in[18];
    const float* jb2  = (const float*)d_in[19];
    float* out  = (float*)d_out;

    const size_t TEN = (size_t)2 * HW * 64;      // elements per bf16 tensor
    unsigned short* bufA = (unsigned short*)d_ws;
    unsigned short* imgT = bufA + TEN;
    unsigned short* gdT  = imgT + TEN;           // dead after fuse3 -> reused as bufC
    unsigned short* wT   = gdT + TEN;
    unsigned short* bufB = (unsigned short*)d_out;   // d_out as scratch until final conv
    unsigned short* bufC = gdT;

    dim3 gs(16, 32, 2);     // 16x8 tiles -> 1024 blocks (slab-swizzled)
    dim3 gw(8, 32, 2);      // jbf 32x8 tiles -> 512 blocks (slab-swizzled)

    // 1: transpose + weight prep (merged)
    k_pre<<<dim3(1024, 12), 256, 0, stream>>>(img, gd, kw1, kw2, kw3, kw4,
                                              jw1, jw2, kw5, tw, imgT, gdT, wT);

    // 2: fused 1x1 + kg1 + kg2
    k_fuse3<<<gs, 256, 0, stream>>>(imgT, gdT, wT + (size_t)7 * 36864,
                                    wT + (size_t)0 * 36864, wT + (size_t)1 * 36864,
                                    tb, kb1, kb2, ajbf, akg, bufA);

    // 3: kg3 + kg4
    k_conv2x<0><<<gs, 256, 0, stream>>>(bufA, wT + (size_t)2 * 36864, wT + (size_t)3 * 36864,
                                        kb3, kb4, akg, nullptr, bufB);

    // 4: jbf combine
    k_jbfm<<<gw, 256, 0, stream>>>(bufB, img, wT + (size_t)6 * 36864, kb5, bufC);

    // 5: jbf conv pair + residual, fp32 NCHW out
    k_conv2x<2><<<gs, 256, 0, stream>>>(bufC, wT + (size_t)4 * 36864, wT + (size_t)5 * 36864,
                                        jb1, jb2, ajbf, img, out);
}

// Round 9
// 282.914 us; speedup vs baseline: 2.6955x; 1.0213x over previous
//
#include <hip/hip_runtime.h>

#define HW 65536

typedef __bf16 bf16x8 __attribute__((ext_vector_type(8)));
typedef float f32x16 __attribute__((ext_vector_type(16)));

__device__ inline unsigned short f2bf(float x) {
    union { float f; unsigned u; } v; v.f = x;
    unsigned r = v.u + 0x7FFF + ((v.u >> 16) & 1);   // RNE
    return (unsigned short)(r >> 16);
}
__device__ inline float bfhi2f(unsigned u) {        // high 16 bits as f32
    union { unsigned u; float f; } v; v.u = u & 0xffff0000u; return v.f;
}
__device__ inline float bflo2f(unsigned u) {        // low 16 bits as f32
    union { unsigned u; float f; } v; v.u = u << 16; return v.f;
}

union FragU { uint4 u; bf16x8 v; };
__device__ inline bf16x8 ld_frag(const uint4* p) { FragU t; t.u = *p; return t.v; }

// XCD-slab swizzle: XCD = lin & 7 (dispatch round-robin). Slab s owns a
// contiguous 64-row band of one batch: b = s>>2, rows [(s&3)*64, +64).

// ---------------------------------------------------------------------------
// k_pre: merged transpose (y<4) + weight prep (y>=4).
// ---------------------------------------------------------------------------
__global__ __launch_bounds__(256) void k_pre(
    const float* __restrict__ img, const float* __restrict__ gd,
    const float* __restrict__ w0, const float* __restrict__ w1,
    const float* __restrict__ w2, const float* __restrict__ w3,
    const float* __restrict__ w4, const float* __restrict__ w5,
    const float* __restrict__ w5c, const float* __restrict__ tw,
    unsigned short* __restrict__ imgT, unsigned short* __restrict__ gdT,
    unsigned short* __restrict__ wT)
{
    __shared__ float sT[64 * 66];
    int tid = threadIdx.x;
    int y = blockIdx.y;
    if (y < 4) {
        int z = y;                  // tensor*2 + b
        int b = z & 1;
        const float* src = (z >> 1) ? gd : img;
        unsigned short* dst = (z >> 1) ? gdT : imgT;
        int px0 = blockIdx.x * 64;
        size_t sbase = (size_t)b * 64 * HW + px0;

#pragma unroll
        for (int i = 0; i < 4; ++i) {
            int e = i * 256 + tid;
            int ic = e >> 4, seg = e & 15;
            float4 v = *(const float4*)(src + sbase + (size_t)ic * HW + seg * 4);
            float* p = &sT[ic * 66 + seg * 4];
            ((float2*)p)[0] = make_float2(v.x, v.y);
            ((float2*)p)[1] = make_float2(v.z, v.w);
        }
        __syncthreads();

        size_t dbase = (size_t)b * HW * 64 + (size_t)px0 * 64;
#pragma unroll
        for (int k = 0; k < 2; ++k) {
            int idx = k * 256 + tid;
            int px = idx >> 3, u = idx & 7;
            union { uint4 q; unsigned short h[8]; } o;
#pragma unroll
            for (int j = 0; j < 8; ++j)
                o.h[j] = f2bf(sT[(u * 8 + j) * 66 + px]);
            *(uint4*)(dst + dbase + (size_t)px * 64 + u * 8) = o.q;
        }
    } else {
        int y2 = y - 4;
        unsigned short* o = wT + (size_t)y2 * 36864;
        int e = blockIdx.x * 256 + tid;
        if (y2 < 6) {
            const float* ws_[6] = {w0, w1, w2, w3, w4, w5};
            const float* w = ws_[y2];
            if (e < 36864) {
                int tap = e >> 12, oc = (e >> 6) & 63, ic = e & 63;
                int igg = ic >> 3, j = ic & 7;
                int dst = ((tap * 8 + igg) * 64 + oc) * 8 + j;
                o[dst] = f2bf(w[(oc * 64 + ic) * 9 + tap]);
            }
        } else if (y2 == 6) {
            if (e < 36864) o[e] = f2bf(w5c[e]);
        } else {
            if (e < 8192) {
                int oc = e >> 7, ic = e & 127;
                int kg = ic >> 3, j = ic & 7;
                o[((kg * 64 + oc) << 3) + j] = f2bf(tw[e]);
            }
        }
    }
}

// ---------------------------------------------------------------------------
// k_fuse3: 1x1(2C->C)+PReLU(ajbf) + 3x3+PReLU(akg) + 3x3+PReLU(akg).
// (round-8, unchanged)
// ---------------------------------------------------------------------------
__global__ __launch_bounds__(256, 2) void k_fuse3(
    const unsigned short* __restrict__ imgT, const unsigned short* __restrict__ gdT,
    const unsigned short* __restrict__ wTf,
    const unsigned short* __restrict__ w1T, const unsigned short* __restrict__ w2T,
    const float* __restrict__ tb, const float* __restrict__ b1,
    const float* __restrict__ b2, const float* __restrict__ ajbf,
    const float* __restrict__ akg, unsigned short* __restrict__ out)
{
    __shared__ __align__(16) char smem[54528];
    float* sB = (float*)(smem + 53760);
    uint4* sS0 = (uint4*)smem;
    uint4* sS1 = (uint4*)(smem + 19200);

    int tid = threadIdx.x;
    int wv = tid >> 6, lane = tid & 63;
    int half = lane >> 5, l31 = lane & 31;
    int w2 = wv >> 1, g = wv & 1;
    int lin = blockIdx.x + (blockIdx.y << 4) + (blockIdx.z << 9);  // [0,1024)
    int slab = lin & 7, sub = lin >> 3;
    int b = slab >> 2;
    int y0 = (slab & 3) * 64 + (sub >> 4) * 8;
    int x0 = (sub & 15) * 16;
    const size_t zbase = (size_t)b * HW * 64;
    const uint4* wgf = (const uint4*)wTf;
    const uint4* wg1 = (const uint4*)w1T;
    const uint4* wg2 = (const uint4*)w2T;

    if (tid < 64) sB[tid] = tb[tid];
    else if (tid < 128) sB[tid] = b1[tid - 64];
    else if (tid < 192) sB[tid] = b2[tid - 128];

    auto loadS = [&](int t, int h, uint4* rx) {
        const unsigned short* src = t ? gdT : imgT;
#pragma unroll
        for (int i = 0; i < 4; ++i) {
            int e = i * 256 + tid;               // active < 960
            int cell = e >> 2, ig = e & 3;
            int r = cell / 20, c2 = cell - r * 20;
            int gy = y0 - 2 + r, gx = x0 - 2 + c2;
            rx[i] = make_uint4(0, 0, 0, 0);
            if (e < 960 && gy >= 0 && gy < 256 && gx >= 0 && gx < 256)
                rx[i] = *(const uint4*)(src + zbase + ((size_t)(gy * 256 + gx)) * 64 + h * 32 + ig * 8);
        }
    };
    auto writeS = [&](uint4* s, const uint4* rx) {
#pragma unroll
        for (int i = 0; i < 4; ++i) {
            int e = i * 256 + tid;
            if (e < 960) s[(e >> 2) * 5 + (e & 3)] = rx[i];
        }
    };

    int cell0[4];
#pragma unroll
    for (int s = 0; s < 4; ++s) {
        int c = g * 128 + s * 32 + l31;
        cell0[s] = c < 240 ? c : 239;
    }
    f32x16 acc0[4];
#pragma unroll
    for (int s = 0; s < 4; ++s)
#pragma unroll
        for (int r = 0; r < 16; ++r) acc0[s][r] = 0.f;

    auto mm1 = [&](int t, int h, const uint4* sS) {
#pragma unroll
        for (int c = 0; c < 2; ++c) {
            int ig = c * 2 + half;
            int kg = t * 8 + h * 4 + ig;
            bf16x8 af = ld_frag(&wgf[kg * 64 + w2 * 32 + l31]);
#pragma unroll
            for (int s = 0; s < 4; ++s) {
                bf16x8 bb = ld_frag(&sS[cell0[s] * 5 + ig]);
                acc0[s] = __builtin_amdgcn_mfma_f32_32x32x16_bf16(af, bb, acc0[s], 0, 0, 0);
            }
        }
    };

    uint4 rx[4];
    loadS(0, 0, rx);
    writeS(sS0, rx);
    loadS(0, 1, rx);            // prefetch p1
    __syncthreads();
    mm1(0, 0, sS0);
    writeS(sS1, rx);
    loadS(1, 0, rx);            // prefetch p2
    __syncthreads();
    mm1(0, 1, sS1);
    writeS(sS0, rx);
    loadS(1, 1, rx);            // prefetch p3
    __syncthreads();
    mm1(1, 0, sS0);
    writeS(sS1, rx);
    __syncthreads();
    mm1(1, 1, sS1);

    float s_jbf = ajbf[0], s_kg = akg[0];
    __syncthreads();
    unsigned short* sC0 = (unsigned short*)smem;
#pragma unroll
    for (int s = 0; s < 4; ++s) {
        int cell = g * 128 + s * 32 + l31;
        if (cell < 240) {
            int R = cell / 20, C = cell - R * 20;
            int gy = y0 - 2 + R, gx = x0 - 2 + C;
            bool inb = (gy >= 0 && gy < 256 && gx >= 0 && gx < 256);
#pragma unroll
            for (int q2 = 0; q2 < 4; ++q2) {
                unsigned short hw[4];
#pragma unroll
                for (int j = 0; j < 4; ++j) {
                    int r = (q2 << 2) | j;
                    int oc = w2 * 32 + j + 8 * q2 + 4 * half;
                    float v = acc0[s][r] + sB[oc];
                    v = (v >= 0.f) ? v : s_jbf * v;
                    if (!inb) v = 0.f;
                    hw[j] = f2bf(v);
                }
                int up = (w2 * 4 + q2) ^ (cell & 7);
                *(uint2*)&sC0[cell * 64 + up * 8 + half * 4] =
                    make_uint2((unsigned)hw[0] | ((unsigned)hw[1] << 16),
                               (unsigned)hw[2] | ((unsigned)hw[3] << 16));
            }
        }
    }
    __syncthreads();

    int cellv[3], ibv[3];
#pragma unroll
    for (int s = 0; s < 3; ++s) {
        int c = g * 96 + s * 32 + l31;
        cellv[s] = c;
        int cc = c < 180 ? c : 179;
        ibv[s] = (cc / 18) * 20 + (cc % 18);
    }
    f32x16 acc1[3];
#pragma unroll
    for (int s = 0; s < 3; ++s)
#pragma unroll
        for (int r = 0; r < 16; ++r) acc1[s][r] = 0.f;

    {
        const uint4* sC04 = (const uint4*)smem;
#pragma unroll
        for (int dy = 0; dy < 3; ++dy) {
#pragma unroll
            for (int dx = 0; dx < 3; ++dx) {
                int tap = dy * 3 + dx;
                int doff = dy * 20 + dx;
#pragma unroll
                for (int c4 = 0; c4 < 4; ++c4) {
                    int unit = c4 * 2 + half;
                    bf16x8 af = ld_frag(&wg1[(tap * 8 + unit) * 64 + w2 * 32 + l31]);
#pragma unroll
                    for (int s = 0; s < 3; ++s) {
                        int cc = ibv[s] + doff;
                        bf16x8 bb = ld_frag(&sC04[cc * 8 + (unit ^ (cc & 7))]);
                        acc1[s] = __builtin_amdgcn_mfma_f32_32x32x16_bf16(af, bb, acc1[s], 0, 0, 0);
                    }
                }
            }
        }
    }

    unsigned short* sC1 = (unsigned short*)(smem + 30720);
#pragma unroll
    for (int s = 0; s < 3; ++s) {
        int cell = cellv[s];
        if (cell < 180) {
            int orow = cell / 18, ocol = cell - orow * 18;
            int gy = y0 - 1 + orow, gx = x0 - 1 + ocol;
            bool inb = (gy >= 0 && gy < 256 && gx >= 0 && gx < 256);
#pragma unroll
            for (int q2 = 0; q2 < 4; ++q2) {
                unsigned short hw[4];
#pragma unroll
                for (int j = 0; j < 4; ++j) {
                    int r = (q2 << 2) | j;
                    int oc = w2 * 32 + j + 8 * q2 + 4 * half;
                    float v = acc1[s][r] + sB[64 + oc];
                    v = (v >= 0.f) ? v : s_kg * v;
                    if (!inb) v = 0.f;
                    hw[j] = f2bf(v);
                }
                int up = (w2 * 4 + q2) ^ (cell & 7);
                *(uint2*)&sC1[cell * 64 + up * 8 + half * 4] =
                    make_uint2((unsigned)hw[0] | ((unsigned)hw[1] << 16),
                               (unsigned)hw[2] | ((unsigned)hw[3] << 16));
            }
        }
    }
    __syncthreads();

    f32x16 acc2[2];
#pragma unroll
    for (int s = 0; s < 2; ++s)
#pragma unroll
        for (int r = 0; r < 16; ++r) acc2[s][r] = 0.f;

    int rowS[2], colS[2];
#pragma unroll
    for (int s = 0; s < 2; ++s) {
        int px = g * 64 + s * 32 + l31;
        rowS[s] = px >> 4; colS[s] = px & 15;
    }
    {
        const uint4* sC14 = (const uint4*)(smem + 30720);
#pragma unroll
        for (int dy = 0; dy < 3; ++dy) {
#pragma unroll
            for (int dx = 0; dx < 3; ++dx) {
                int tap = dy * 3 + dx;
#pragma unroll
                for (int c = 0; c < 4; ++c) {
                    int ig = c * 2 + half;
                    bf16x8 af = ld_frag(&wg2[(tap * 8 + ig) * 64 + w2 * 32 + l31]);
#pragma unroll
                    for (int s = 0; s < 2; ++s) {
                        int cl = (rowS[s] + dy) * 18 + colS[s] + dx;
                        bf16x8 bb = ld_frag(&sC14[cl * 8 + (ig ^ (cl & 7))]);
                        acc2[s] = __builtin_amdgcn_mfma_f32_32x32x16_bf16(af, bb, acc2[s], 0, 0, 0);
                    }
                }
            }
        }
    }

    unsigned short* sT16 = (unsigned short*)smem;
#pragma unroll
    for (int s = 0; s < 2; ++s) {
        int px = g * 64 + s * 32 + l31;
#pragma unroll
        for (int q2 = 0; q2 < 4; ++q2) {
            unsigned short hw[4];
#pragma unroll
            for (int j = 0; j < 4; ++j) {
                int r = (q2 << 2) | j;
                int oc = w2 * 32 + j + 8 * q2 + 4 * half;
                float v = acc2[s][r] + sB[128 + oc];
                v = (v >= 0.f) ? v : s_kg * v;
                hw[j] = f2bf(v);
            }
            int up = (w2 * 4 + q2) ^ (px & 7);
            uint2* p = (uint2*)&sT16[px * 64 + up * 8 + half * 4];
            *p = make_uint2((unsigned)hw[0] | ((unsigned)hw[1] << 16),
                            (unsigned)hw[2] | ((unsigned)hw[3] << 16));
        }
    }
    __syncthreads();
#pragma unroll
    for (int k = 0; k < 4; ++k) {
        int idx = k * 256 + tid;
        int row = idx >> 7, rem = idx & 127;
        int col = rem >> 3, u = rem & 7;
        int px = row * 16 + col;
        uint4 v = *(uint4*)&sT16[px * 64 + (u ^ (px & 7)) * 8];
        *(uint4*)(out + zbase + ((size_t)((y0 + row) * 256 + x0 + col)) * 64 + u * 8) = v;
    }
}

// ---------------------------------------------------------------------------
// k_conv2x: fused pair of 3x3 convs (round-7; only MODE 2 instantiated now).
// ---------------------------------------------------------------------------
#define XU 5

template<int MODE>
__global__ __launch_bounds__(256, 4) void k_conv2x(
    const unsigned short* __restrict__ in,
    const unsigned short* __restrict__ w1T, const unsigned short* __restrict__ w2T,
    const float* __restrict__ b1, const float* __restrict__ b2,
    const float* __restrict__ a, const float* __restrict__ res,
    void* __restrict__ outv)
{
    __shared__ __align__(16) char smem[38912];
    uint4* sIn0 = (uint4*)smem;
    uint4* sIn1 = (uint4*)(smem + 19200);
    float* sB = (float*)(smem + 38400);

    int tid = threadIdx.x;
    int wv = tid >> 6, lane = tid & 63;
    int half = lane >> 5, l31 = lane & 31;
    int w2 = wv >> 1, g = wv & 1;
    int lin = blockIdx.x + (blockIdx.y << 4) + (blockIdx.z << 9);
    int slab = lin & 7, sub = lin >> 3;
    int b = slab >> 2;
    int y0 = (slab & 3) * 64 + (sub >> 4) * 8;
    int x0 = (sub & 15) * 16;
    const size_t zbase = (size_t)b * HW * 64;
    const uint4* wg1 = (const uint4*)w1T;
    const uint4* wg2 = (const uint4*)w2T;

    if (tid < 64) sB[tid] = b1[tid];
    else if (tid < 128) sB[tid] = b2[tid - 64];

    auto loadIn = [&](int h, uint4* rx) {
#pragma unroll
        for (int i = 0; i < 4; ++i) {
            int e = i * 256 + tid;
            int cell = e >> 2, ig = e & 3;
            int r = cell / 20, c2 = cell - r * 20;
            int gy = y0 - 2 + r, gx = x0 - 2 + c2;
            rx[i] = make_uint4(0, 0, 0, 0);
            bool act = (i < 3) || (e < 960);
            if (act && gy >= 0 && gy < 256 && gx >= 0 && gx < 256)
                rx[i] = *(const uint4*)(in + zbase + ((size_t)(gy * 256 + gx)) * 64 + h * 32 + ig * 8);
        }
    };
    auto writeIn = [&](uint4* s, const uint4* rx) {
#pragma unroll
        for (int i = 0; i < 4; ++i) {
            int e = i * 256 + tid;
            if (i < 3 || e < 960) s[(e >> 2) * XU + (e & 3)] = rx[i];
        }
    };

    int cellv[3], ibv[3];
#pragma unroll
    for (int s = 0; s < 3; ++s) {
        int c = g * 96 + s * 32 + l31;
        cellv[s] = c;
        int cc = c < 180 ? c : 179;
        ibv[s] = (cc / 18) * 20 + (cc % 18);
    }

    f32x16 acc1[3];
#pragma unroll
    for (int s = 0; s < 3; ++s)
#pragma unroll
        for (int r = 0; r < 16; ++r) acc1[s][r] = 0.f;

    auto conv1_h = [&](int h, const uint4* sInp) {
#pragma unroll
        for (int dy = 0; dy < 3; ++dy) {
#pragma unroll
            for (int dx = 0; dx < 3; ++dx) {
                int tap = dy * 3 + dx;
                int doff = dy * 20 + dx;
#pragma unroll
                for (int c = 0; c < 2; ++c) {
                    int ig = c * 2 + half;
                    bf16x8 af = ld_frag(&wg1[(tap * 8 + h * 4 + ig) * 64 + w2 * 32 + l31]);
#pragma unroll
                    for (int s = 0; s < 3; ++s) {
                        bf16x8 bb = ld_frag(&sInp[(ibv[s] + doff) * XU + ig]);
                        acc1[s] = __builtin_amdgcn_mfma_f32_32x32x16_bf16(af, bb, acc1[s], 0, 0, 0);
                    }
                }
            }
        }
    };

    uint4 rx[4];
    loadIn(0, rx);
    writeIn(sIn0, rx);
    uint4 ry[4];
    loadIn(1, ry);
    __syncthreads();
    conv1_h(0, sIn0);
    writeIn(sIn1, ry);
    __syncthreads();
    conv1_h(1, sIn1);

    float s1 = a[0];
    __syncthreads();
    unsigned short* sC16 = (unsigned short*)smem;
#pragma unroll
    for (int s = 0; s < 3; ++s) {
        int cell = cellv[s];
        if (cell < 180) {
            int orow = cell / 18, ocol = cell - orow * 18;
            int gy = y0 - 1 + orow, gx = x0 - 1 + ocol;
            bool inb = (gy >= 0 && gy < 256 && gx >= 0 && gx < 256);
#pragma unroll
            for (int q2 = 0; q2 < 4; ++q2) {
                unsigned short hw[4];
#pragma unroll
                for (int j = 0; j < 4; ++j) {
                    int r = (q2 << 2) | j;
                    int oc = w2 * 32 + j + 8 * q2 + 4 * half;
                    float v = acc1[s][r] + sB[oc];
                    v = (v >= 0.f) ? v : s1 * v;
                    if (!inb) v = 0.f;
                    hw[j] = f2bf(v);
                }
                int up = (w2 * 4 + q2) ^ (cell & 7);
                *(uint2*)&sC16[cell * 64 + up * 8 + half * 4] =
                    make_uint2((unsigned)hw[0] | ((unsigned)hw[1] << 16),
                               (unsigned)hw[2] | ((unsigned)hw[3] << 16));
            }
        }
    }
    __syncthreads();

    f32x16 acc2[2];
#pragma unroll
    for (int s = 0; s < 2; ++s)
#pragma unroll
        for (int r = 0; r < 16; ++r) acc2[s][r] = 0.f;

    int rowS[2], colS[2];
#pragma unroll
    for (int s = 0; s < 2; ++s) {
        int px = g * 64 + s * 32 + l31;
        rowS[s] = px >> 4; colS[s] = px & 15;
    }
    {
        const uint4* sC4 = (const uint4*)smem;
#pragma unroll
        for (int dy = 0; dy < 3; ++dy) {
#pragma unroll
            for (int dx = 0; dx < 3; ++dx) {
                int tap = dy * 3 + dx;
#pragma unroll
                for (int c = 0; c < 4; ++c) {
                    int ig = c * 2 + half;
                    bf16x8 af = ld_frag(&wg2[(tap * 8 + ig) * 64 + w2 * 32 + l31]);
#pragma unroll
                    for (int s = 0; s < 2; ++s) {
                        int cl = (rowS[s] + dy) * 18 + colS[s] + dx;
                        bf16x8 bb = ld_frag(&sC4[cl * 8 + (ig ^ (cl & 7))]);
                        acc2[s] = __builtin_amdgcn_mfma_f32_32x32x16_bf16(af, bb, acc2[s], 0, 0, 0);
                    }
                }
            }
        }
    }

    if (MODE == 0) {
        __syncthreads();
        unsigned short* sT16 = (unsigned short*)smem;
#pragma unroll
        for (int s = 0; s < 2; ++s) {
            int px = g * 64 + s * 32 + l31;
#pragma unroll
            for (int q2 = 0; q2 < 4; ++q2) {
                unsigned short hw[4];
#pragma unroll
                for (int j = 0; j < 4; ++j) {
                    int r = (q2 << 2) | j;
                    int oc = w2 * 32 + j + 8 * q2 + 4 * half;
                    float v = acc2[s][r] + sB[64 + oc];
                    v = (v >= 0.f) ? v : s1 * v;
                    hw[j] = f2bf(v);
                }
                int up = (w2 * 4 + q2) ^ (px & 7);
                uint2* p = (uint2*)&sT16[px * 64 + up * 8 + half * 4];
                *p = make_uint2((unsigned)hw[0] | ((unsigned)hw[1] << 16),
                                (unsigned)hw[2] | ((unsigned)hw[3] << 16));
            }
        }
        __syncthreads();
        unsigned short* outT = (unsigned short*)outv;
#pragma unroll
        for (int k = 0; k < 4; ++k) {
            int idx = k * 256 + tid;
            int row = idx >> 7, rem = idx & 127;
            int col = rem >> 3, u = rem & 7;
            int px = row * 16 + col;
            uint4 v = *(uint4*)&sT16[px * 64 + (u ^ (px & 7)) * 8];
            *(uint4*)(outT + zbase + ((size_t)((y0 + row) * 256 + x0 + col)) * 64 + u * 8) = v;
        }
    } else {
        float* outF = (float*)outv;
#pragma unroll
        for (int s = 0; s < 2; ++s) {
            int px = g * 64 + s * 32 + l31;
            int y = y0 + (px >> 4), x = x0 + (px & 15);
            size_t pbase = (size_t)b * 64 * HW + (size_t)y * 256 + x;
#pragma unroll
            for (int r = 0; r < 16; ++r) {
                int oc = w2 * 32 + (r & 3) + 8 * (r >> 2) + 4 * half;
                float v = acc2[s][r] + sB[64 + oc];
                v += res[pbase + (size_t)oc * HW];
                outF[pbase + (size_t)oc * HW] = v;
            }
        }
    }
}

// ---------------------------------------------------------------------------
// k_jbfm5: FUSED kg3+PReLU + kg4+PReLU + kg_w5(C->576) + combine.
// One 32x8 jbfm tile per block (512 blocks, slab-swizzled).
// Conv pair computed on exact tile (conv1 halo 34x10=340 cells, input halo
// 36x12=432 cells from bufA). conv2 output written directly into jbfm's sY
// LDS layout [px*9+ig] -> no global y4 round-trip, no sY staging.
// LDS phases: sIn dbuf 2x34560 @0/@34560 -> sC 43520 @0 -> sY 36864 @43520
// (persists); jbfm overlays @0: sW5 dbuf 16384, sP dbuf 23040 @16384,
// sB5 @39424; conv biases @80384. Total 80896 B -> 2 blocks/CU.
// ---------------------------------------------------------------------------
struct OffTab { unsigned v[9][32]; int chlo[9]; };
constexpr OffTab make_tab() {
    OffTab t{};
    for (int kk = 0; kk < 9; ++kk) {
        int chlo = (kk * 64) / 9;
        t.chlo[kk] = chlo;
        for (int ot = 0; ot < 2; ++ot)
            for (int r = 0; r < 16; ++r) {
                int cc0 = ot * 32 + (r & 3) + 8 * (r >> 2);
                int q0 = kk * 64 + cc0, q1 = q0 + 4;
                int o0 = (q0 / 9 - chlo) * 360 + (q0 % 9 / 3) * 40 + (q0 % 9 % 3);
                int o1 = (q1 / 9 - chlo) * 360 + (q1 % 9 / 3) * 40 + (q1 % 9 % 3);
                t.v[kk][ot * 16 + r] = (unsigned)o0 | ((unsigned)o1 << 16);
            }
    }
    return t;
}
__constant__ OffTab kOff = make_tab();

__global__ __launch_bounds__(256, 2) void k_jbfm5(
    const unsigned short* __restrict__ in, const float* __restrict__ img,
    const unsigned short* __restrict__ w1T, const unsigned short* __restrict__ w2T,
    const unsigned short* __restrict__ w5T,
    const float* __restrict__ b1, const float* __restrict__ b2,
    const float* __restrict__ b5, const float* __restrict__ akg,
    unsigned short* __restrict__ out)
{
    __shared__ __align__(16) char smem[80896];
    float* sB = (float*)(smem + 80384);          // [0..63]=b1(kg3) [64..127]=b2(kg4)
    uint4* sIn0 = (uint4*)smem;                  // 2160 uint4
    uint4* sIn1 = (uint4*)(smem + 34560);
    uint4* sY = (uint4*)(smem + 43520);          // 2304 uint4 [px*9+ig], persists
    float* sB5 = (float*)(smem + 39424);         // 576 f32 (jbfm phase)
    unsigned short* sT16 = (unsigned short*)smem;// epilogue overlay 32KB

    int tid = threadIdx.x;
    int wv = tid >> 6, lane = tid & 63;
    int half = lane >> 5, l31 = lane & 31;
    int w2 = wv >> 1, g = wv & 1;
    int lin = blockIdx.x + (blockIdx.y << 3) + (blockIdx.z << 8);  // [0,512)
    int slab = lin & 7, sub = lin >> 3;
    int b = slab >> 2;
    int y0 = (slab & 3) * 64 + (sub >> 3) * 8;
    int x0 = (sub & 7) * 32;
    size_t zbase = (size_t)b * HW * 64;          // NHWC base
    size_t ibase = (size_t)b * 64 * HW;          // NCHW base (img)
    const uint4* wg1 = (const uint4*)w1T;
    const uint4* wg2 = (const uint4*)w2T;

    if (tid < 64) sB[tid] = b1[tid];
    else if (tid < 128) sB[tid] = b2[tid - 64];

    // ---- conv staging: 432 cells (12x36 halo, origin y0-2,x0-2) ----
    auto loadIn = [&](int h, uint4* rx) {
#pragma unroll
        for (int i = 0; i < 7; ++i) {
            int e = i * 256 + tid;               // active < 1728
            int cell = e >> 2, ig = e & 3;
            int r = cell / 36, c2 = cell - r * 36;
            int gy = y0 - 2 + r, gx = x0 - 2 + c2;
            rx[i] = make_uint4(0, 0, 0, 0);
            if (e < 1728 && gy >= 0 && gy < 256 && gx >= 0 && gx < 256)
                rx[i] = *(const uint4*)(in + zbase + ((size_t)(gy * 256 + gx)) * 64 + h * 32 + ig * 8);
        }
    };
    auto writeIn = [&](uint4* s, const uint4* rx) {
#pragma unroll
        for (int i = 0; i < 7; ++i) {
            int e = i * 256 + tid;
            if (e < 1728) s[(e >> 2) * XU + (e & 3)] = rx[i];
        }
    };

    // ---- conv1 (kg3): output-halo 34x10 = 340 cells; (w2,g) split, 6 slots ----
    int cellv[6], ibv[6];
    bool val[6];
#pragma unroll
    for (int s = 0; s < 6; ++s) {
        int c = g * 170 + s * 32 + l31;
        val[s] = (s * 32 + l31) < 170;
        cellv[s] = c;
        int cc = c < 340 ? c : 339;
        ibv[s] = (cc / 34) * 36 + (cc % 34);
    }
    f32x16 acc1[6];
#pragma unroll
    for (int s = 0; s < 6; ++s)
#pragma unroll
        for (int r = 0; r < 16; ++r) acc1[s][r] = 0.f;

    auto conv1_h = [&](int h, const uint4* sInp) {
#pragma unroll
        for (int dy = 0; dy < 3; ++dy) {
#pragma unroll
            for (int dx = 0; dx < 3; ++dx) {
                int tap = dy * 3 + dx;
                int doff = dy * 36 + dx;
#pragma unroll
                for (int c = 0; c < 2; ++c) {
                    int ig = c * 2 + half;
                    bf16x8 af = ld_frag(&wg1[(tap * 8 + h * 4 + ig) * 64 + w2 * 32 + l31]);
#pragma unroll
                    for (int s = 0; s < 6; ++s) {
                        bf16x8 bb = ld_frag(&sInp[(ibv[s] + doff) * XU + ig]);
                        acc1[s] = __builtin_amdgcn_mfma_f32_32x32x16_bf16(af, bb, acc1[s], 0, 0, 0);
                    }
                }
            }
        }
    };

    uint4 rx[7], ry[7];
    loadIn(0, rx);
    writeIn(sIn0, rx);
    loadIn(1, ry);          // prefetch h1
    __syncthreads();
    conv1_h(0, sIn0);
    writeIn(sIn1, ry);
    __syncthreads();
    conv1_h(1, sIn1);

    // epi1: b1 + PReLU(akg), OOB zero, pack -> sC @0 (overlays sIn)
    float s_kg = akg[0];
    __syncthreads();
    unsigned short* sC16 = (unsigned short*)smem;
#pragma unroll
    for (int s = 0; s < 6; ++s) {
        if (val[s]) {
            int cell = cellv[s];
            int row = cell / 34, col = cell - row * 34;
            int gy = y0 - 1 + row, gx = x0 - 1 + col;
            bool inb = (gy >= 0 && gy < 256 && gx >= 0 && gx < 256);
#pragma unroll
            for (int q2 = 0; q2 < 4; ++q2) {
                unsigned short hw[4];
#pragma unroll
                for (int j = 0; j < 4; ++j) {
                    int r = (q2 << 2) | j;
                    int oc = w2 * 32 + j + 8 * q2 + 4 * half;
                    float v = acc1[s][r] + sB[oc];
                    v = (v >= 0.f) ? v : s_kg * v;
                    if (!inb) v = 0.f;
                    hw[j] = f2bf(v);
                }
                int up = (w2 * 4 + q2) ^ (cell & 7);
                *(uint2*)&sC16[cell * 64 + up * 8 + half * 4] =
                    make_uint2((unsigned)hw[0] | ((unsigned)hw[1] << 16),
                               (unsigned)hw[2] | ((unsigned)hw[3] << 16));
            }
        }
    }
    __syncthreads();        // sC ready

    // ---- conv2 (kg4): 32x8 output; (w2,g) split, 4 slots of 32 px ----
    f32x16 acc2[4];
#pragma unroll
    for (int s = 0; s < 4; ++s)
#pragma unroll
        for (int r = 0; r < 16; ++r) acc2[s][r] = 0.f;

    int rowS[4], colS[4];
#pragma unroll
    for (int s = 0; s < 4; ++s) {
        int p = g * 128 + s * 32 + l31;
        rowS[s] = p >> 5; colS[s] = p & 31;
    }
    {
        const uint4* sC4 = (const uint4*)smem;
#pragma unroll
        for (int dy = 0; dy < 3; ++dy) {
#pragma unroll
            for (int dx = 0; dx < 3; ++dx) {
                int tap = dy * 3 + dx;
#pragma unroll
                for (int c = 0; c < 4; ++c) {
                    int ig = c * 2 + half;
                    bf16x8 af = ld_frag(&wg2[(tap * 8 + ig) * 64 + w2 * 32 + l31]);
#pragma unroll
                    for (int s = 0; s < 4; ++s) {
                        int cl = (rowS[s] + dy) * 34 + colS[s] + dx;
                        bf16x8 bb = ld_frag(&sC4[cl * 8 + (ig ^ (cl & 7))]);
                        acc2[s] = __builtin_amdgcn_mfma_f32_32x32x16_bf16(af, bb, acc2[s], 0, 0, 0);
                    }
                }
            }
        }
    }

    // epi2: b2 + PReLU(akg) -> sY (unswizzled jbfm layout, disjoint from sC)
    {
        unsigned short* sY16 = (unsigned short*)(smem + 43520);
#pragma unroll
        for (int s = 0; s < 4; ++s) {
            int px = g * 128 + s * 32 + l31;
#pragma unroll
            for (int q2 = 0; q2 < 4; ++q2) {
                int ig = w2 * 4 + q2;
                unsigned short hw[4];
#pragma unroll
                for (int j = 0; j < 4; ++j) {
                    int r = (q2 << 2) | j;
                    int oc = w2 * 32 + j + 8 * q2 + 4 * half;
                    float v = acc2[s][r] + sB[64 + oc];
                    v = (v >= 0.f) ? v : s_kg * v;
                    hw[j] = f2bf(v);
                }
                *(uint2*)&sY16[px * 72 + ig * 8 + half * 4] =
                    make_uint2((unsigned)hw[0] | ((unsigned)hw[1] << 16),
                               (unsigned)hw[2] | ((unsigned)hw[3] << 16));
            }
        }
    }
    __syncthreads();        // all sC reads + sY writes done; safe to overlay @0

    // ---- jbfm phase ----
    int p_off[3], p_dst[3];
    bool p_a[3], p_b[3], p_act[3];
#pragma unroll
    for (int i = 0; i < 3; ++i) {
        int e = i * 256 + tid;
        bool act = e < 720;
        int ch = e / 90, rem = e - ch * 90;
        int rp = rem / 10, seg = rem - rp * 10;
        int gy = y0 + rp - 1;
        int gxb = x0 - 4 + seg * 4;
        bool xok = (gxb >= 0 && gxb < 256);
        p_act[i] = act;
        p_a[i] = act && xok && gy >= 0 && gy < 256;
        p_b[i] = act && xok && (gy + 1) < 256;
        p_off[i] = ch * HW + gy * 256 + gxb;
        p_dst[i] = ch * 360 + rp * 40 + seg * 4;
    }

    for (int e = tid; e < 576; e += 256) sB5[e] = b5[e];

    {
        uint4* sW50 = (uint4*)smem;              // buffer 0 @0
        unsigned* sP0 = (unsigned*)(smem + 16384);
#pragma unroll
        for (int u = 0; u < 2; ++u) {
            int uu = u * 256 + tid;
            int cc = uu & 63, ig = uu >> 6;
            sW50[uu] = ((const uint4*)w5T)[cc * 8 + ig];
        }
        const float* rp0 = img + ibase;
#pragma unroll
        for (int i = 0; i < 3; ++i) {
            float4 fa = make_float4(0, 0, 0, 0), fb = make_float4(0, 0, 0, 0);
            if (p_a[i]) fa = *(const float4*)(rp0 + p_off[i]);
            if (p_b[i]) fb = *(const float4*)(rp0 + p_off[i] + 256);
            if (p_act[i]) {
                uint4 pk;
                pk.x = (unsigned)f2bf(fa.x) | ((unsigned)f2bf(fb.x) << 16);
                pk.y = (unsigned)f2bf(fa.y) | ((unsigned)f2bf(fb.y) << 16);
                pk.z = (unsigned)f2bf(fa.z) | ((unsigned)f2bf(fb.z) << 16);
                pk.w = (unsigned)f2bf(fa.w) | ((unsigned)f2bf(fb.w) << 16);
                *(uint4*)&sP0[p_dst[i]] = pk;
            }
        }
    }

    float jb[2][2][16];
#pragma unroll
    for (int i = 0; i < 2; ++i)
#pragma unroll
        for (int j = 0; j < 2; ++j)
#pragma unroll
            for (int r = 0; r < 16; ++r) jb[i][j][r] = 0.f;

    __syncthreads();

#pragma unroll 1
    for (int kk = 0; kk < 9; ++kk) {
        const int cur = kk & 1;
        const uint4* sW5c = (const uint4*)(smem + cur * 8192);
        const unsigned* sPc = (const unsigned*)(smem + 16384 + cur * 11520);

        uint4 wpre0, wpre1;
        float4 pfa[3], pfb[3];
        if (kk < 8) {
            const int nk = kk + 1;
            const int chlo_n = kOff.chlo[nk];
            {
                int cc = tid & 63, ig = tid >> 6;
                wpre0 = ((const uint4*)w5T)[(nk * 64 + cc) * 8 + ig];
                int uu = 256 + tid;
                int cc1 = uu & 63, ig1 = uu >> 6;
                wpre1 = ((const uint4*)w5T)[(nk * 64 + cc1) * 8 + ig1];
            }
            const float* rp0 = img + ibase + (size_t)chlo_n * HW;
#pragma unroll
            for (int i = 0; i < 3; ++i) {
                pfa[i] = make_float4(0, 0, 0, 0);
                pfb[i] = make_float4(0, 0, 0, 0);
                if (p_a[i]) pfa[i] = *(const float4*)(rp0 + p_off[i]);
                if (p_b[i]) pfb[i] = *(const float4*)(rp0 + p_off[i] + 256);
            }
        }

        f32x16 acc[2][2];
#pragma unroll
        for (int ot = 0; ot < 2; ++ot)
#pragma unroll
            for (int r = 0; r < 16; ++r) {
                int cc0 = ot * 32 + (r & 3) + 8 * (r >> 2);
                float bv = sB5[kk * 64 + cc0 + 4 * half];
                acc[ot][0][r] = bv;
                acc[ot][1][r] = bv;
            }

#pragma unroll
        for (int c = 0; c < 4; ++c) {
            int ig = c * 2 + half;
            bf16x8 a0 = ld_frag(&sW5c[ig * 64 + l31]);
            bf16x8 a1 = ld_frag(&sW5c[ig * 64 + 32 + l31]);
            int p0 = wv * 64 + l31;
            bf16x8 b0 = ld_frag(&sY[p0 * 9 + ig]);
            bf16x8 b1 = ld_frag(&sY[(p0 + 32) * 9 + ig]);
            acc[0][0] = __builtin_amdgcn_mfma_f32_32x32x16_bf16(a0, b0, acc[0][0], 0, 0, 0);
            acc[0][1] = __builtin_amdgcn_mfma_f32_32x32x16_bf16(a0, b1, acc[0][1], 0, 0, 0);
            acc[1][0] = __builtin_amdgcn_mfma_f32_32x32x16_bf16(a1, b0, acc[1][0], 0, 0, 0);
            acc[1][1] = __builtin_amdgcn_mfma_f32_32x32x16_bf16(a1, b1, acc[1][1], 0, 0, 0);
        }

        {
            const unsigned* basep = sPc + wv * 80 + l31 + 3;
            const unsigned* tab = kOff.v[kk];
#pragma unroll
            for (int ot = 0; ot < 2; ++ot)
#pragma unroll
                for (int r = 0; r < 16; ++r) {
                    unsigned oo = tab[ot * 16 + r];
                    unsigned o0 = oo & 0xffffu, o1 = oo >> 16;
                    unsigned pv = basep[half ? o1 : o0];
                    jb[ot][0][r] = fmaf(acc[ot][0][r], bflo2f(pv), jb[ot][0][r]);
                    jb[ot][1][r] = fmaf(acc[ot][1][r], bfhi2f(pv), jb[ot][1][r]);
                }
        }

        if (kk < 8) {
            uint4* sW5n = (uint4*)(smem + (cur ^ 1) * 8192);
            unsigned* sPn = (unsigned*)(smem + 16384 + (cur ^ 1) * 11520);
            sW5n[tid] = wpre0;
            sW5n[256 + tid] = wpre1;
#pragma unroll
            for (int i = 0; i < 3; ++i) {
                if (p_act[i]) {
                    uint4 pk;
                    pk.x = (unsigned)f2bf(pfa[i].x) | ((unsigned)f2bf(pfb[i].x) << 16);
                    pk.y = (unsigned)f2bf(pfa[i].y) | ((unsigned)f2bf(pfb[i].y) << 16);
                    pk.z = (unsigned)f2bf(pfa[i].z) | ((unsigned)f2bf(pfb[i].z) << 16);
                    pk.w = (unsigned)f2bf(pfa[i].w) | ((unsigned)f2bf(pfb[i].w) << 16);
                    *(uint4*)&sPn[p_dst[i]] = pk;
                }
            }
        }
        __syncthreads();
    }

    // epilogue: NHWC bf16 out via swizzled LDS transpose (overlay @0)
#pragma unroll
    for (int ot = 0; ot < 2; ++ot)
#pragma unroll
        for (int pt = 0; pt < 2; ++pt) {
            int px = wv * 64 + pt * 32 + l31;
#pragma unroll
            for (int q2 = 0; q2 < 4; ++q2) {
                unsigned short hw[4];
#pragma unroll
                for (int j = 0; j < 4; ++j) {
                    int r = (q2 << 2) | j;
                    hw[j] = f2bf(jb[ot][pt][r]);
                }
                int unit = ot * 4 + q2;
                int up = unit ^ (px & 7);
                uint2* p = (uint2*)&sT16[px * 64 + up * 8 + half * 4];
                *p = make_uint2((unsigned)hw[0] | ((unsigned)hw[1] << 16),
                                (unsigned)hw[2] | ((unsigned)hw[3] << 16));
            }
        }
    __syncthreads();
#pragma unroll
    for (int k = 0; k < 8; ++k) {
        int col = tid >> 3, u = tid & 7;
        int px = k * 32 + col;
        uint4 v = *(uint4*)&sT16[px * 64 + (u ^ (px & 7)) * 8];
        *(uint4*)(out + zbase + ((size_t)((y0 + k) * 256 + x0 + col)) * 64 + u * 8) = v;
    }
}

// ---------------------------------------------------------------------------
extern "C" void kernel_launch(void* const* d_in, const int* in_sizes, int n_in,
                              void* d_out, int out_size, void* d_ws, size_t ws_size,
                              hipStream_t stream) {
    const float* img  = (const float*)d_in[0];
    const float* gd   = (const float*)d_in[1];
    const float* tw   = (const float*)d_in[2];
    const float* tb   = (const float*)d_in[3];
    const float* ajbf = (const float*)d_in[4];
    const float* kw1  = (const float*)d_in[5];
    const float* kb1  = (const float*)d_in[6];
    const float* kw2  = (const float*)d_in[7];
    const float* kb2  = (const float*)d_in[8];
    const float* kw3  = (const float*)d_in[9];
    const float* kb3  = (const float*)d_in[10];
    const float* kw4  = (const float*)d_in[11];
    const float* kb4  = (const float*)d_in[12];
    const float* kw5  = (const float*)d_in[13];
    const float* kb5  = (const float*)d_in[14];
    const float* akg  = (const float*)d_in[15];
    const float* jw1  = (const float*)d_in[16];
    const float* jb1  = (const float*)d_in[17];
    const float* jw2  = (const float*)d_in[18];
    const float* jb2  = (const float*)d_in[19];
    float* out  = (float*)d_out;

    const size_t TEN = (size_t)2 * HW * 64;      // elements per bf16 tensor
    unsigned short* bufA = (unsigned short*)d_ws;
    unsigned short* imgT = bufA + TEN;
    unsigned short* gdT  = imgT + TEN;           // dead after fuse3 -> reused as bufC
    unsigned short* wT   = gdT + TEN;
    unsigned short* bufC = gdT;

    dim3 gs(16, 32, 2);     // 16x8 tiles -> 1024 blocks (slab-swizzled)
    dim3 gw(8, 32, 2);      // 32x8 tiles -> 512 blocks (slab-swizzled)

    // 1: transpose + weight prep (merged)
    k_pre<<<dim3(1024, 12), 256, 0, stream>>>(img, gd, kw1, kw2, kw3, kw4,
                                              jw1, jw2, kw5, tw, imgT, gdT, wT);

    // 2: fused 1x1 + kg1 + kg2
    k_fuse3<<<gs, 256, 0, stream>>>(imgT, gdT, wT + (size_t)7 * 36864,
                                    wT + (size_t)0 * 36864, wT + (size_t)1 * 36864,
                                    tb, kb1, kb2, ajbf, akg, bufA);

    // 3: fused kg3 + kg4 + jbf combine
    k_jbfm5<<<gw, 256, 0, stream>>>(bufA, img,
                                    wT + (size_t)2 * 36864, wT + (size_t)3 * 36864,
                                    wT + (size_t)6 * 36864,
                                    kb3, kb4, kb5, akg, bufC);

    // 4: jbf conv pair + residual, fp32 NCHW out
    k_conv2x<2><<<gs, 256, 0, stream>>>(bufC, wT + (size_t)4 * 36864, wT + (size_t)5 * 36864,
                                        jb1, jb2, ajbf, img, out);
}

// Round 10
// 272.063 us; speedup vs baseline: 2.8030x; 1.0399x over previous
//
#include <hip/hip_runtime.h>

#define HW 65536

typedef __bf16 bf16x8 __attribute__((ext_vector_type(8)));
typedef float f32x16 __attribute__((ext_vector_type(16)));

__device__ inline unsigned short f2bf(float x) {
    union { float f; unsigned u; } v; v.f = x;
    unsigned r = v.u + 0x7FFF + ((v.u >> 16) & 1);   // RNE
    return (unsigned short)(r >> 16);
}
// packed f32x2 -> bf16x2 (RNE), single HW instruction: low16 = bf(a), high16 = bf(b)
__device__ inline unsigned pk2(float a, float b) {
    unsigned r;
    asm("v_cvt_pk_bf16_f32 %0, %1, %2" : "=v"(r) : "v"(a), "v"(b));
    return r;
}
__device__ inline float bfhi2f(unsigned u) {        // high 16 bits as f32
    union { unsigned u; float f; } v; v.u = u & 0xffff0000u; return v.f;
}
__device__ inline float bflo2f(unsigned u) {        // low 16 bits as f32
    union { unsigned u; float f; } v; v.u = u << 16; return v.f;
}

union FragU { uint4 u; bf16x8 v; };
__device__ inline bf16x8 ld_frag(const uint4* p) { FragU t; t.u = *p; return t.v; }

// XCD-slab swizzle: XCD = lin & 7 (dispatch round-robin). Slab s owns a
// contiguous 64-row band of one batch: b = s>>2, rows [(s&3)*64, +64).

// ---------------------------------------------------------------------------
// k_pre: merged transpose (y<4) + weight prep (y>=4).
// ---------------------------------------------------------------------------
__global__ __launch_bounds__(256) void k_pre(
    const float* __restrict__ img, const float* __restrict__ gd,
    const float* __restrict__ w0, const float* __restrict__ w1,
    const float* __restrict__ w2, const float* __restrict__ w3,
    const float* __restrict__ w4, const float* __restrict__ w5,
    const float* __restrict__ w5c, const float* __restrict__ tw,
    unsigned short* __restrict__ imgT, unsigned short* __restrict__ gdT,
    unsigned short* __restrict__ wT)
{
    __shared__ float sT[64 * 66];
    int tid = threadIdx.x;
    int y = blockIdx.y;
    if (y < 4) {
        int z = y;                  // tensor*2 + b
        int b = z & 1;
        const float* src = (z >> 1) ? gd : img;
        unsigned short* dst = (z >> 1) ? gdT : imgT;
        int px0 = blockIdx.x * 64;
        size_t sbase = (size_t)b * 64 * HW + px0;

#pragma unroll
        for (int i = 0; i < 4; ++i) {
            int e = i * 256 + tid;
            int ic = e >> 4, seg = e & 15;
            float4 v = *(const float4*)(src + sbase + (size_t)ic * HW + seg * 4);
            float* p = &sT[ic * 66 + seg * 4];
            ((float2*)p)[0] = make_float2(v.x, v.y);
            ((float2*)p)[1] = make_float2(v.z, v.w);
        }
        __syncthreads();

        size_t dbase = (size_t)b * HW * 64 + (size_t)px0 * 64;
#pragma unroll
        for (int k = 0; k < 2; ++k) {
            int idx = k * 256 + tid;
            int px = idx >> 3, u = idx & 7;
            union { uint4 q; unsigned w[4]; } ou;
#pragma unroll
            for (int j = 0; j < 4; ++j)
                ou.w[j] = pk2(sT[(u * 8 + 2 * j) * 66 + px],
                              sT[(u * 8 + 2 * j + 1) * 66 + px]);
            *(uint4*)(dst + dbase + (size_t)px * 64 + u * 8) = ou.q;
        }
    } else {
        int y2 = y - 4;
        unsigned short* o = wT + (size_t)y2 * 36864;
        int e = blockIdx.x * 256 + tid;
        if (y2 < 6) {
            const float* ws_[6] = {w0, w1, w2, w3, w4, w5};
            const float* w = ws_[y2];
            if (e < 36864) {
                int tap = e >> 12, oc = (e >> 6) & 63, ic = e & 63;
                int igg = ic >> 3, j = ic & 7;
                int dst = ((tap * 8 + igg) * 64 + oc) * 8 + j;
                o[dst] = f2bf(w[(oc * 64 + ic) * 9 + tap]);
            }
        } else if (y2 == 6) {
            if (e < 36864) o[e] = f2bf(w5c[e]);
        } else {
            if (e < 8192) {
                int oc = e >> 7, ic = e & 127;
                int kg = ic >> 3, j = ic & 7;
                o[((kg * 64 + oc) << 3) + j] = f2bf(tw[e]);
            }
        }
    }
}

// ---------------------------------------------------------------------------
// k_fuse3: 1x1(2C->C)+PReLU(ajbf) + 3x3+PReLU(akg) + 3x3+PReLU(akg).
// (round-8 structure; + cvt_pk packing, setprio around MFMA clusters)
// ---------------------------------------------------------------------------
__global__ __launch_bounds__(256, 2) void k_fuse3(
    const unsigned short* __restrict__ imgT, const unsigned short* __restrict__ gdT,
    const unsigned short* __restrict__ wTf,
    const unsigned short* __restrict__ w1T, const unsigned short* __restrict__ w2T,
    const float* __restrict__ tb, const float* __restrict__ b1,
    const float* __restrict__ b2, const float* __restrict__ ajbf,
    const float* __restrict__ akg, unsigned short* __restrict__ out)
{
    __shared__ __align__(16) char smem[54528];
    float* sB = (float*)(smem + 53760);
    uint4* sS0 = (uint4*)smem;
    uint4* sS1 = (uint4*)(smem + 19200);

    int tid = threadIdx.x;
    int wv = tid >> 6, lane = tid & 63;
    int half = lane >> 5, l31 = lane & 31;
    int w2 = wv >> 1, g = wv & 1;
    int lin = blockIdx.x + (blockIdx.y << 4) + (blockIdx.z << 9);  // [0,1024)
    int slab = lin & 7, sub = lin >> 3;
    int b = slab >> 2;
    int y0 = (slab & 3) * 64 + (sub >> 4) * 8;
    int x0 = (sub & 15) * 16;
    const size_t zbase = (size_t)b * HW * 64;
    const uint4* wgf = (const uint4*)wTf;
    const uint4* wg1 = (const uint4*)w1T;
    const uint4* wg2 = (const uint4*)w2T;

    if (tid < 64) sB[tid] = tb[tid];
    else if (tid < 128) sB[tid] = b1[tid - 64];
    else if (tid < 192) sB[tid] = b2[tid - 128];

    auto loadS = [&](int t, int h, uint4* rx) {
        const unsigned short* src = t ? gdT : imgT;
#pragma unroll
        for (int i = 0; i < 4; ++i) {
            int e = i * 256 + tid;               // active < 960
            int cell = e >> 2, ig = e & 3;
            int r = cell / 20, c2 = cell - r * 20;
            int gy = y0 - 2 + r, gx = x0 - 2 + c2;
            rx[i] = make_uint4(0, 0, 0, 0);
            if (e < 960 && gy >= 0 && gy < 256 && gx >= 0 && gx < 256)
                rx[i] = *(const uint4*)(src + zbase + ((size_t)(gy * 256 + gx)) * 64 + h * 32 + ig * 8);
        }
    };
    auto writeS = [&](uint4* s, const uint4* rx) {
#pragma unroll
        for (int i = 0; i < 4; ++i) {
            int e = i * 256 + tid;
            if (e < 960) s[(e >> 2) * 5 + (e & 3)] = rx[i];
        }
    };

    int cell0[4];
#pragma unroll
    for (int s = 0; s < 4; ++s) {
        int c = g * 128 + s * 32 + l31;
        cell0[s] = c < 240 ? c : 239;
    }
    f32x16 acc0[4];
#pragma unroll
    for (int s = 0; s < 4; ++s)
#pragma unroll
        for (int r = 0; r < 16; ++r) acc0[s][r] = 0.f;

    auto mm1 = [&](int t, int h, const uint4* sS) {
        __builtin_amdgcn_s_setprio(1);
#pragma unroll
        for (int c = 0; c < 2; ++c) {
            int ig = c * 2 + half;
            int kg = t * 8 + h * 4 + ig;
            bf16x8 af = ld_frag(&wgf[kg * 64 + w2 * 32 + l31]);
#pragma unroll
            for (int s = 0; s < 4; ++s) {
                bf16x8 bb = ld_frag(&sS[cell0[s] * 5 + ig]);
                acc0[s] = __builtin_amdgcn_mfma_f32_32x32x16_bf16(af, bb, acc0[s], 0, 0, 0);
            }
        }
        __builtin_amdgcn_s_setprio(0);
    };

    uint4 rx[4];
    loadS(0, 0, rx);
    writeS(sS0, rx);
    loadS(0, 1, rx);            // prefetch p1
    __syncthreads();
    mm1(0, 0, sS0);
    writeS(sS1, rx);
    loadS(1, 0, rx);            // prefetch p2
    __syncthreads();
    mm1(0, 1, sS1);
    writeS(sS0, rx);
    loadS(1, 1, rx);            // prefetch p3
    __syncthreads();
    mm1(1, 0, sS0);
    writeS(sS1, rx);
    __syncthreads();
    mm1(1, 1, sS1);

    float s_jbf = ajbf[0], s_kg = akg[0];
    __syncthreads();
    unsigned short* sC0 = (unsigned short*)smem;
#pragma unroll
    for (int s = 0; s < 4; ++s) {
        int cell = g * 128 + s * 32 + l31;
        if (cell < 240) {
            int R = cell / 20, C = cell - R * 20;
            int gy = y0 - 2 + R, gx = x0 - 2 + C;
            bool inb = (gy >= 0 && gy < 256 && gx >= 0 && gx < 256);
#pragma unroll
            for (int q2 = 0; q2 < 4; ++q2) {
                float vv[4];
#pragma unroll
                for (int j = 0; j < 4; ++j) {
                    int r = (q2 << 2) | j;
                    int oc = w2 * 32 + j + 8 * q2 + 4 * half;
                    float v = acc0[s][r] + sB[oc];
                    v = (v >= 0.f) ? v : s_jbf * v;
                    vv[j] = inb ? v : 0.f;
                }
                int up = (w2 * 4 + q2) ^ (cell & 7);
                *(uint2*)&sC0[cell * 64 + up * 8 + half * 4] =
                    make_uint2(pk2(vv[0], vv[1]), pk2(vv[2], vv[3]));
            }
        }
    }
    __syncthreads();

    int cellv[3], ibv[3];
#pragma unroll
    for (int s = 0; s < 3; ++s) {
        int c = g * 96 + s * 32 + l31;
        cellv[s] = c;
        int cc = c < 180 ? c : 179;
        ibv[s] = (cc / 18) * 20 + (cc % 18);
    }
    f32x16 acc1[3];
#pragma unroll
    for (int s = 0; s < 3; ++s)
#pragma unroll
        for (int r = 0; r < 16; ++r) acc1[s][r] = 0.f;

    {
        const uint4* sC04 = (const uint4*)smem;
        __builtin_amdgcn_s_setprio(1);
#pragma unroll
        for (int dy = 0; dy < 3; ++dy) {
#pragma unroll
            for (int dx = 0; dx < 3; ++dx) {
                int tap = dy * 3 + dx;
                int doff = dy * 20 + dx;
#pragma unroll
                for (int c4 = 0; c4 < 4; ++c4) {
                    int unit = c4 * 2 + half;
                    bf16x8 af = ld_frag(&wg1[(tap * 8 + unit) * 64 + w2 * 32 + l31]);
#pragma unroll
                    for (int s = 0; s < 3; ++s) {
                        int cc = ibv[s] + doff;
                        bf16x8 bb = ld_frag(&sC04[cc * 8 + (unit ^ (cc & 7))]);
                        acc1[s] = __builtin_amdgcn_mfma_f32_32x32x16_bf16(af, bb, acc1[s], 0, 0, 0);
                    }
                }
            }
        }
        __builtin_amdgcn_s_setprio(0);
    }

    unsigned short* sC1 = (unsigned short*)(smem + 30720);
#pragma unroll
    for (int s = 0; s < 3; ++s) {
        int cell = cellv[s];
        if (cell < 180) {
            int orow = cell / 18, ocol = cell - orow * 18;
            int gy = y0 - 1 + orow, gx = x0 - 1 + ocol;
            bool inb = (gy >= 0 && gy < 256 && gx >= 0 && gx < 256);
#pragma unroll
            for (int q2 = 0; q2 < 4; ++q2) {
                float vv[4];
#pragma unroll
                for (int j = 0; j < 4; ++j) {
                    int r = (q2 << 2) | j;
                    int oc = w2 * 32 + j + 8 * q2 + 4 * half;
                    float v = acc1[s][r] + sB[64 + oc];
                    v = (v >= 0.f) ? v : s_kg * v;
                    vv[j] = inb ? v : 0.f;
                }
                int up = (w2 * 4 + q2) ^ (cell & 7);
                *(uint2*)&sC1[cell * 64 + up * 8 + half * 4] =
                    make_uint2(pk2(vv[0], vv[1]), pk2(vv[2], vv[3]));
            }
        }
    }
    __syncthreads();

    f32x16 acc2[2];
#pragma unroll
    for (int s = 0; s < 2; ++s)
#pragma unroll
        for (int r = 0; r < 16; ++r) acc2[s][r] = 0.f;

    int rowS[2], colS[2];
#pragma unroll
    for (int s = 0; s < 2; ++s) {
        int px = g * 64 + s * 32 + l31;
        rowS[s] = px >> 4; colS[s] = px & 15;
    }
    {
        const uint4* sC14 = (const uint4*)(smem + 30720);
        __builtin_amdgcn_s_setprio(1);
#pragma unroll
        for (int dy = 0; dy < 3; ++dy) {
#pragma unroll
            for (int dx = 0; dx < 3; ++dx) {
                int tap = dy * 3 + dx;
#pragma unroll
                for (int c = 0; c < 4; ++c) {
                    int ig = c * 2 + half;
                    bf16x8 af = ld_frag(&wg2[(tap * 8 + ig) * 64 + w2 * 32 + l31]);
#pragma unroll
                    for (int s = 0; s < 2; ++s) {
                        int cl = (rowS[s] + dy) * 18 + colS[s] + dx;
                        bf16x8 bb = ld_frag(&sC14[cl * 8 + (ig ^ (cl & 7))]);
                        acc2[s] = __builtin_amdgcn_mfma_f32_32x32x16_bf16(af, bb, acc2[s], 0, 0, 0);
                    }
                }
            }
        }
        __builtin_amdgcn_s_setprio(0);
    }

    unsigned short* sT16 = (unsigned short*)smem;
#pragma unroll
    for (int s = 0; s < 2; ++s) {
        int px = g * 64 + s * 32 + l31;
#pragma unroll
        for (int q2 = 0; q2 < 4; ++q2) {
            float vv[4];
#pragma unroll
            for (int j = 0; j < 4; ++j) {
                int r = (q2 << 2) | j;
                int oc = w2 * 32 + j + 8 * q2 + 4 * half;
                float v = acc2[s][r] + sB[128 + oc];
                vv[j] = (v >= 0.f) ? v : s_kg * v;
            }
            int up = (w2 * 4 + q2) ^ (px & 7);
            uint2* p = (uint2*)&sT16[px * 64 + up * 8 + half * 4];
            *p = make_uint2(pk2(vv[0], vv[1]), pk2(vv[2], vv[3]));
        }
    }
    __syncthreads();
#pragma unroll
    for (int k = 0; k < 4; ++k) {
        int idx = k * 256 + tid;
        int row = idx >> 7, rem = idx & 127;
        int col = rem >> 3, u = rem & 7;
        int px = row * 16 + col;
        uint4 v = *(uint4*)&sT16[px * 64 + (u ^ (px & 7)) * 8];
        *(uint4*)(out + zbase + ((size_t)((y0 + row) * 256 + x0 + col)) * 64 + u * 8) = v;
    }
}

// ---------------------------------------------------------------------------
// k_conv2x: fused pair of 3x3 convs (round-7; only MODE 2 instantiated).
// ---------------------------------------------------------------------------
#define XU 5

template<int MODE>
__global__ __launch_bounds__(256, 4) void k_conv2x(
    const unsigned short* __restrict__ in,
    const unsigned short* __restrict__ w1T, const unsigned short* __restrict__ w2T,
    const float* __restrict__ b1, const float* __restrict__ b2,
    const float* __restrict__ a, const float* __restrict__ res,
    void* __restrict__ outv)
{
    __shared__ __align__(16) char smem[38912];
    uint4* sIn0 = (uint4*)smem;
    uint4* sIn1 = (uint4*)(smem + 19200);
    float* sB = (float*)(smem + 38400);

    int tid = threadIdx.x;
    int wv = tid >> 6, lane = tid & 63;
    int half = lane >> 5, l31 = lane & 31;
    int w2 = wv >> 1, g = wv & 1;
    int lin = blockIdx.x + (blockIdx.y << 4) + (blockIdx.z << 9);
    int slab = lin & 7, sub = lin >> 3;
    int b = slab >> 2;
    int y0 = (slab & 3) * 64 + (sub >> 4) * 8;
    int x0 = (sub & 15) * 16;
    const size_t zbase = (size_t)b * HW * 64;
    const uint4* wg1 = (const uint4*)w1T;
    const uint4* wg2 = (const uint4*)w2T;

    if (tid < 64) sB[tid] = b1[tid];
    else if (tid < 128) sB[tid] = b2[tid - 64];

    auto loadIn = [&](int h, uint4* rx) {
#pragma unroll
        for (int i = 0; i < 4; ++i) {
            int e = i * 256 + tid;
            int cell = e >> 2, ig = e & 3;
            int r = cell / 20, c2 = cell - r * 20;
            int gy = y0 - 2 + r, gx = x0 - 2 + c2;
            rx[i] = make_uint4(0, 0, 0, 0);
            bool act = (i < 3) || (e < 960);
            if (act && gy >= 0 && gy < 256 && gx >= 0 && gx < 256)
                rx[i] = *(const uint4*)(in + zbase + ((size_t)(gy * 256 + gx)) * 64 + h * 32 + ig * 8);
        }
    };
    auto writeIn = [&](uint4* s, const uint4* rx) {
#pragma unroll
        for (int i = 0; i < 4; ++i) {
            int e = i * 256 + tid;
            if (i < 3 || e < 960) s[(e >> 2) * XU + (e & 3)] = rx[i];
        }
    };

    int cellv[3], ibv[3];
#pragma unroll
    for (int s = 0; s < 3; ++s) {
        int c = g * 96 + s * 32 + l31;
        cellv[s] = c;
        int cc = c < 180 ? c : 179;
        ibv[s] = (cc / 18) * 20 + (cc % 18);
    }

    f32x16 acc1[3];
#pragma unroll
    for (int s = 0; s < 3; ++s)
#pragma unroll
        for (int r = 0; r < 16; ++r) acc1[s][r] = 0.f;

    auto conv1_h = [&](int h, const uint4* sInp) {
        __builtin_amdgcn_s_setprio(1);
#pragma unroll
        for (int dy = 0; dy < 3; ++dy) {
#pragma unroll
            for (int dx = 0; dx < 3; ++dx) {
                int tap = dy * 3 + dx;
                int doff = dy * 20 + dx;
#pragma unroll
                for (int c = 0; c < 2; ++c) {
                    int ig = c * 2 + half;
                    bf16x8 af = ld_frag(&wg1[(tap * 8 + h * 4 + ig) * 64 + w2 * 32 + l31]);
#pragma unroll
                    for (int s = 0; s < 3; ++s) {
                        bf16x8 bb = ld_frag(&sInp[(ibv[s] + doff) * XU + ig]);
                        acc1[s] = __builtin_amdgcn_mfma_f32_32x32x16_bf16(af, bb, acc1[s], 0, 0, 0);
                    }
                }
            }
        }
        __builtin_amdgcn_s_setprio(0);
    };

    uint4 rx[4];
    loadIn(0, rx);
    writeIn(sIn0, rx);
    uint4 ry[4];
    loadIn(1, ry);
    __syncthreads();
    conv1_h(0, sIn0);
    writeIn(sIn1, ry);
    __syncthreads();
    conv1_h(1, sIn1);

    float s1 = a[0];
    __syncthreads();
    unsigned short* sC16 = (unsigned short*)smem;
#pragma unroll
    for (int s = 0; s < 3; ++s) {
        int cell = cellv[s];
        if (cell < 180) {
            int orow = cell / 18, ocol = cell - orow * 18;
            int gy = y0 - 1 + orow, gx = x0 - 1 + ocol;
            bool inb = (gy >= 0 && gy < 256 && gx >= 0 && gx < 256);
#pragma unroll
            for (int q2 = 0; q2 < 4; ++q2) {
                float vv[4];
#pragma unroll
                for (int j = 0; j < 4; ++j) {
                    int r = (q2 << 2) | j;
                    int oc = w2 * 32 + j + 8 * q2 + 4 * half;
                    float v = acc1[s][r] + sB[oc];
                    v = (v >= 0.f) ? v : s1 * v;
                    vv[j] = inb ? v : 0.f;
                }
                int up = (w2 * 4 + q2) ^ (cell & 7);
                *(uint2*)&sC16[cell * 64 + up * 8 + half * 4] =
                    make_uint2(pk2(vv[0], vv[1]), pk2(vv[2], vv[3]));
            }
        }
    }
    __syncthreads();

    f32x16 acc2[2];
#pragma unroll
    for (int s = 0; s < 2; ++s)
#pragma unroll
        for (int r = 0; r < 16; ++r) acc2[s][r] = 0.f;

    int rowS[2], colS[2];
#pragma unroll
    for (int s = 0; s < 2; ++s) {
        int px = g * 64 + s * 32 + l31;
        rowS[s] = px >> 4; colS[s] = px & 15;
    }
    {
        const uint4* sC4 = (const uint4*)smem;
        __builtin_amdgcn_s_setprio(1);
#pragma unroll
        for (int dy = 0; dy < 3; ++dy) {
#pragma unroll
            for (int dx = 0; dx < 3; ++dx) {
                int tap = dy * 3 + dx;
#pragma unroll
                for (int c = 0; c < 4; ++c) {
                    int ig = c * 2 + half;
                    bf16x8 af = ld_frag(&wg2[(tap * 8 + ig) * 64 + w2 * 32 + l31]);
#pragma unroll
                    for (int s = 0; s < 2; ++s) {
                        int cl = (rowS[s] + dy) * 18 + colS[s] + dx;
                        bf16x8 bb = ld_frag(&sC4[cl * 8 + (ig ^ (cl & 7))]);
                        acc2[s] = __builtin_amdgcn_mfma_f32_32x32x16_bf16(af, bb, acc2[s], 0, 0, 0);
                    }
                }
            }
        }
        __builtin_amdgcn_s_setprio(0);
    }

    if (MODE == 0) {
        __syncthreads();
        unsigned short* sT16 = (unsigned short*)smem;
#pragma unroll
        for (int s = 0; s < 2; ++s) {
            int px = g * 64 + s * 32 + l31;
#pragma unroll
            for (int q2 = 0; q2 < 4; ++q2) {
                float vv[4];
#pragma unroll
                for (int j = 0; j < 4; ++j) {
                    int r = (q2 << 2) | j;
                    int oc = w2 * 32 + j + 8 * q2 + 4 * half;
                    float v = acc2[s][r] + sB[64 + oc];
                    vv[j] = (v >= 0.f) ? v : s1 * v;
                }
                int up = (w2 * 4 + q2) ^ (px & 7);
                uint2* p = (uint2*)&sT16[px * 64 + up * 8 + half * 4];
                *p = make_uint2(pk2(vv[0], vv[1]), pk2(vv[2], vv[3]));
            }
        }
        __syncthreads();
        unsigned short* outT = (unsigned short*)outv;
#pragma unroll
        for (int k = 0; k < 4; ++k) {
            int idx = k * 256 + tid;
            int row = idx >> 7, rem = idx & 127;
            int col = rem >> 3, u = rem & 7;
            int px = row * 16 + col;
            uint4 v = *(uint4*)&sT16[px * 64 + (u ^ (px & 7)) * 8];
            *(uint4*)(outT + zbase + ((size_t)((y0 + row) * 256 + x0 + col)) * 64 + u * 8) = v;
        }
    } else {
        float* outF = (float*)outv;
#pragma unroll
        for (int s = 0; s < 2; ++s) {
            int px = g * 64 + s * 32 + l31;
            int y = y0 + (px >> 4), x = x0 + (px & 15);
            size_t pbase = (size_t)b * 64 * HW + (size_t)y * 256 + x;
#pragma unroll
            for (int r = 0; r < 16; ++r) {
                int oc = w2 * 32 + (r & 3) + 8 * (r >> 2) + 4 * half;
                float v = acc2[s][r] + sB[64 + oc];
                v += res[pbase + (size_t)oc * HW];
                outF[pbase + (size_t)oc * HW] = v;
            }
        }
    }
}

// ---------------------------------------------------------------------------
// k_jbfm5: FUSED kg3+PReLU + kg4+PReLU + kg_w5(C->576) + combine.
// (round-9 structure; + cvt_pk packing, setprio around MFMA clusters)
// ---------------------------------------------------------------------------
struct OffTab { unsigned v[9][32]; int chlo[9]; };
constexpr OffTab make_tab() {
    OffTab t{};
    for (int kk = 0; kk < 9; ++kk) {
        int chlo = (kk * 64) / 9;
        t.chlo[kk] = chlo;
        for (int ot = 0; ot < 2; ++ot)
            for (int r = 0; r < 16; ++r) {
                int cc0 = ot * 32 + (r & 3) + 8 * (r >> 2);
                int q0 = kk * 64 + cc0, q1 = q0 + 4;
                int o0 = (q0 / 9 - chlo) * 360 + (q0 % 9 / 3) * 40 + (q0 % 9 % 3);
                int o1 = (q1 / 9 - chlo) * 360 + (q1 % 9 / 3) * 40 + (q1 % 9 % 3);
                t.v[kk][ot * 16 + r] = (unsigned)o0 | ((unsigned)o1 << 16);
            }
    }
    return t;
}
__constant__ OffTab kOff = make_tab();

__global__ __launch_bounds__(256, 2) void k_jbfm5(
    const unsigned short* __restrict__ in, const float* __restrict__ img,
    const unsigned short* __restrict__ w1T, const unsigned short* __restrict__ w2T,
    const unsigned short* __restrict__ w5T,
    const float* __restrict__ b1, const float* __restrict__ b2,
    const float* __restrict__ b5, const float* __restrict__ akg,
    unsigned short* __restrict__ out)
{
    __shared__ __align__(16) char smem[80896];
    float* sB = (float*)(smem + 80384);          // [0..63]=b1(kg3) [64..127]=b2(kg4)
    uint4* sIn0 = (uint4*)smem;                  // 2160 uint4
    uint4* sIn1 = (uint4*)(smem + 34560);
    uint4* sY = (uint4*)(smem + 43520);          // 2304 uint4 [px*9+ig], persists
    float* sB5 = (float*)(smem + 39424);         // 576 f32 (jbfm phase)
    unsigned short* sT16 = (unsigned short*)smem;// epilogue overlay 32KB

    int tid = threadIdx.x;
    int wv = tid >> 6, lane = tid & 63;
    int half = lane >> 5, l31 = lane & 31;
    int w2 = wv >> 1, g = wv & 1;
    int lin = blockIdx.x + (blockIdx.y << 3) + (blockIdx.z << 8);  // [0,512)
    int slab = lin & 7, sub = lin >> 3;
    int b = slab >> 2;
    int y0 = (slab & 3) * 64 + (sub >> 3) * 8;
    int x0 = (sub & 7) * 32;
    size_t zbase = (size_t)b * HW * 64;          // NHWC base
    size_t ibase = (size_t)b * 64 * HW;          // NCHW base (img)
    const uint4* wg1 = (const uint4*)w1T;
    const uint4* wg2 = (const uint4*)w2T;

    if (tid < 64) sB[tid] = b1[tid];
    else if (tid < 128) sB[tid] = b2[tid - 64];

    // ---- conv staging: 432 cells (12x36 halo, origin y0-2,x0-2) ----
    auto loadIn = [&](int h, uint4* rx) {
#pragma unroll
        for (int i = 0; i < 7; ++i) {
            int e = i * 256 + tid;               // active < 1728
            int cell = e >> 2, ig = e & 3;
            int r = cell / 36, c2 = cell - r * 36;
            int gy = y0 - 2 + r, gx = x0 - 2 + c2;
            rx[i] = make_uint4(0, 0, 0, 0);
            if (e < 1728 && gy >= 0 && gy < 256 && gx >= 0 && gx < 256)
                rx[i] = *(const uint4*)(in + zbase + ((size_t)(gy * 256 + gx)) * 64 + h * 32 + ig * 8);
        }
    };
    auto writeIn = [&](uint4* s, const uint4* rx) {
#pragma unroll
        for (int i = 0; i < 7; ++i) {
            int e = i * 256 + tid;
            if (e < 1728) s[(e >> 2) * XU + (e & 3)] = rx[i];
        }
    };

    // ---- conv1 (kg3): output-halo 34x10 = 340 cells; (w2,g) split, 6 slots ----
    int cellv[6], ibv[6];
    bool val[6];
#pragma unroll
    for (int s = 0; s < 6; ++s) {
        int c = g * 170 + s * 32 + l31;
        val[s] = (s * 32 + l31) < 170;
        cellv[s] = c;
        int cc = c < 340 ? c : 339;
        ibv[s] = (cc / 34) * 36 + (cc % 34);
    }
    f32x16 acc1[6];
#pragma unroll
    for (int s = 0; s < 6; ++s)
#pragma unroll
        for (int r = 0; r < 16; ++r) acc1[s][r] = 0.f;

    auto conv1_h = [&](int h, const uint4* sInp) {
        __builtin_amdgcn_s_setprio(1);
#pragma unroll
        for (int dy = 0; dy < 3; ++dy) {
#pragma unroll
            for (int dx = 0; dx < 3; ++dx) {
                int tap = dy * 3 + dx;
                int doff = dy * 36 + dx;
#pragma unroll
                for (int c = 0; c < 2; ++c) {
                    int ig = c * 2 + half;
                    bf16x8 af = ld_frag(&wg1[(tap * 8 + h * 4 + ig) * 64 + w2 * 32 + l31]);
#pragma unroll
                    for (int s = 0; s < 6; ++s) {
                        bf16x8 bb = ld_frag(&sInp[(ibv[s] + doff) * XU + ig]);
                        acc1[s] = __builtin_amdgcn_mfma_f32_32x32x16_bf16(af, bb, acc1[s], 0, 0, 0);
                    }
                }
            }
        }
        __builtin_amdgcn_s_setprio(0);
    };

    uint4 rx[7], ry[7];
    loadIn(0, rx);
    writeIn(sIn0, rx);
    loadIn(1, ry);          // prefetch h1
    __syncthreads();
    conv1_h(0, sIn0);
    writeIn(sIn1, ry);
    __syncthreads();
    conv1_h(1, sIn1);

    // epi1: b1 + PReLU(akg), OOB zero, pack -> sC @0 (overlays sIn)
    float s_kg = akg[0];
    __syncthreads();
    unsigned short* sC16 = (unsigned short*)smem;
#pragma unroll
    for (int s = 0; s < 6; ++s) {
        if (val[s]) {
            int cell = cellv[s];
            int row = cell / 34, col = cell - row * 34;
            int gy = y0 - 1 + row, gx = x0 - 1 + col;
            bool inb = (gy >= 0 && gy < 256 && gx >= 0 && gx < 256);
#pragma unroll
            for (int q2 = 0; q2 < 4; ++q2) {
                float vv[4];
#pragma unroll
                for (int j = 0; j < 4; ++j) {
                    int r = (q2 << 2) | j;
                    int oc = w2 * 32 + j + 8 * q2 + 4 * half;
                    float v = acc1[s][r] + sB[oc];
                    v = (v >= 0.f) ? v : s_kg * v;
                    vv[j] = inb ? v : 0.f;
                }
                int up = (w2 * 4 + q2) ^ (cell & 7);
                *(uint2*)&sC16[cell * 64 + up * 8 + half * 4] =
                    make_uint2(pk2(vv[0], vv[1]), pk2(vv[2], vv[3]));
            }
        }
    }
    __syncthreads();        // sC ready

    // ---- conv2 (kg4): 32x8 output; (w2,g) split, 4 slots of 32 px ----
    f32x16 acc2[4];
#pragma unroll
    for (int s = 0; s < 4; ++s)
#pragma unroll
        for (int r = 0; r < 16; ++r) acc2[s][r] = 0.f;

    int rowS[4], colS[4];
#pragma unroll
    for (int s = 0; s < 4; ++s) {
        int p = g * 128 + s * 32 + l31;
        rowS[s] = p >> 5; colS[s] = p & 31;
    }
    {
        const uint4* sC4 = (const uint4*)smem;
        __builtin_amdgcn_s_setprio(1);
#pragma unroll
        for (int dy = 0; dy < 3; ++dy) {
#pragma unroll
            for (int dx = 0; dx < 3; ++dx) {
                int tap = dy * 3 + dx;
#pragma unroll
                for (int c = 0; c < 4; ++c) {
                    int ig = c * 2 + half;
                    bf16x8 af = ld_frag(&wg2[(tap * 8 + ig) * 64 + w2 * 32 + l31]);
#pragma unroll
                    for (int s = 0; s < 4; ++s) {
                        int cl = (rowS[s] + dy) * 34 + colS[s] + dx;
                        bf16x8 bb = ld_frag(&sC4[cl * 8 + (ig ^ (cl & 7))]);
                        acc2[s] = __builtin_amdgcn_mfma_f32_32x32x16_bf16(af, bb, acc2[s], 0, 0, 0);
                    }
                }
            }
        }
        __builtin_amdgcn_s_setprio(0);
    }

    // epi2: b2 + PReLU(akg) -> sY (unswizzled jbfm layout, disjoint from sC)
    {
        unsigned short* sY16 = (unsigned short*)(smem + 43520);
#pragma unroll
        for (int s = 0; s < 4; ++s) {
            int px = g * 128 + s * 32 + l31;
#pragma unroll
            for (int q2 = 0; q2 < 4; ++q2) {
                int ig = w2 * 4 + q2;
                float vv[4];
#pragma unroll
                for (int j = 0; j < 4; ++j) {
                    int r = (q2 << 2) | j;
                    int oc = w2 * 32 + j + 8 * q2 + 4 * half;
                    float v = acc2[s][r] + sB[64 + oc];
                    vv[j] = (v >= 0.f) ? v : s_kg * v;
                }
                *(uint2*)&sY16[px * 72 + ig * 8 + half * 4] =
                    make_uint2(pk2(vv[0], vv[1]), pk2(vv[2], vv[3]));
            }
        }
    }
    __syncthreads();        // all sC reads + sY writes done; safe to overlay @0

    // ---- jbfm phase ----
    int p_off[3], p_dst[3];
    bool p_a[3], p_b[3], p_act[3];
#pragma unroll
    for (int i = 0; i < 3; ++i) {
        int e = i * 256 + tid;
        bool act = e < 720;
        int ch = e / 90, rem = e - ch * 90;
        int rp = rem / 10, seg = rem - rp * 10;
        int gy = y0 + rp - 1;
        int gxb = x0 - 4 + seg * 4;
        bool xok = (gxb >= 0 && gxb < 256);
        p_act[i] = act;
        p_a[i] = act && xok && gy >= 0 && gy < 256;
        p_b[i] = act && xok && (gy + 1) < 256;
        p_off[i] = ch * HW + gy * 256 + gxb;
        p_dst[i] = ch * 360 + rp * 40 + seg * 4;
    }

    for (int e = tid; e < 576; e += 256) sB5[e] = b5[e];

    {
        uint4* sW50 = (uint4*)smem;              // buffer 0 @0
        unsigned* sP0 = (unsigned*)(smem + 16384);
#pragma unroll
        for (int u = 0; u < 2; ++u) {
            int uu = u * 256 + tid;
            int cc = uu & 63, ig = uu >> 6;
            sW50[uu] = ((const uint4*)w5T)[cc * 8 + ig];
        }
        const float* rp0 = img + ibase;
#pragma unroll
        for (int i = 0; i < 3; ++i) {
            float4 fa = make_float4(0, 0, 0, 0), fb = make_float4(0, 0, 0, 0);
            if (p_a[i]) fa = *(const float4*)(rp0 + p_off[i]);
            if (p_b[i]) fb = *(const float4*)(rp0 + p_off[i] + 256);
            if (p_act[i]) {
                uint4 pk;
                pk.x = pk2(fa.x, fb.x);
                pk.y = pk2(fa.y, fb.y);
                pk.z = pk2(fa.z, fb.z);
                pk.w = pk2(fa.w, fb.w);
                *(uint4*)&sP0[p_dst[i]] = pk;
            }
        }
    }

    float jb[2][2][16];
#pragma unroll
    for (int i = 0; i < 2; ++i)
#pragma unroll
        for (int j = 0; j < 2; ++j)
#pragma unroll
            for (int r = 0; r < 16; ++r) jb[i][j][r] = 0.f;

    __syncthreads();

#pragma unroll 1
    for (int kk = 0; kk < 9; ++kk) {
        const int cur = kk & 1;
        const uint4* sW5c = (const uint4*)(smem + cur * 8192);
        const unsigned* sPc = (const unsigned*)(smem + 16384 + cur * 11520);

        uint4 wpre0, wpre1;
        float4 pfa[3], pfb[3];
        if (kk < 8) {
            const int nk = kk + 1;
            const int chlo_n = kOff.chlo[nk];
            {
                int cc = tid & 63, ig = tid >> 6;
                wpre0 = ((const uint4*)w5T)[(nk * 64 + cc) * 8 + ig];
                int uu = 256 + tid;
                int cc1 = uu & 63, ig1 = uu >> 6;
                wpre1 = ((const uint4*)w5T)[(nk * 64 + cc1) * 8 + ig1];
            }
            const float* rp0 = img + ibase + (size_t)chlo_n * HW;
#pragma unroll
            for (int i = 0; i < 3; ++i) {
                pfa[i] = make_float4(0, 0, 0, 0);
                pfb[i] = make_float4(0, 0, 0, 0);
                if (p_a[i]) pfa[i] = *(const float4*)(rp0 + p_off[i]);
                if (p_b[i]) pfb[i] = *(const float4*)(rp0 + p_off[i] + 256);
            }
        }

        f32x16 acc[2][2];
#pragma unroll
        for (int ot = 0; ot < 2; ++ot)
#pragma unroll
            for (int r = 0; r < 16; ++r) {
                int cc0 = ot * 32 + (r & 3) + 8 * (r >> 2);
                float bv = sB5[kk * 64 + cc0 + 4 * half];
                acc[ot][0][r] = bv;
                acc[ot][1][r] = bv;
            }

        __builtin_amdgcn_s_setprio(1);
#pragma unroll
        for (int c = 0; c < 4; ++c) {
            int ig = c * 2 + half;
            bf16x8 a0 = ld_frag(&sW5c[ig * 64 + l31]);
            bf16x8 a1 = ld_frag(&sW5c[ig * 64 + 32 + l31]);
            int p0 = wv * 64 + l31;
            bf16x8 b0 = ld_frag(&sY[p0 * 9 + ig]);
            bf16x8 b1 = ld_frag(&sY[(p0 + 32) * 9 + ig]);
            acc[0][0] = __builtin_amdgcn_mfma_f32_32x32x16_bf16(a0, b0, acc[0][0], 0, 0, 0);
            acc[0][1] = __builtin_amdgcn_mfma_f32_32x32x16_bf16(a0, b1, acc[0][1], 0, 0, 0);
            acc[1][0] = __builtin_amdgcn_mfma_f32_32x32x16_bf16(a1, b0, acc[1][0], 0, 0, 0);
            acc[1][1] = __builtin_amdgcn_mfma_f32_32x32x16_bf16(a1, b1, acc[1][1], 0, 0, 0);
        }
        __builtin_amdgcn_s_setprio(0);

        {
            const unsigned* basep = sPc + wv * 80 + l31 + 3;
            const unsigned* tab = kOff.v[kk];
#pragma unroll
            for (int ot = 0; ot < 2; ++ot)
#pragma unroll
                for (int r = 0; r < 16; ++r) {
                    unsigned oo = tab[ot * 16 + r];
                    unsigned o0 = oo & 0xffffu, o1 = oo >> 16;
                    unsigned pv = basep[half ? o1 : o0];
                    jb[ot][0][r] = fmaf(acc[ot][0][r], bflo2f(pv), jb[ot][0][r]);
                    jb[ot][1][r] = fmaf(acc[ot][1][r], bfhi2f(pv), jb[ot][1][r]);
                }
        }

        if (kk < 8) {
            uint4* sW5n = (uint4*)(smem + (cur ^ 1) * 8192);
            unsigned* sPn = (unsigned*)(smem + 16384 + (cur ^ 1) * 11520);
            sW5n[tid] = wpre0;
            sW5n[256 + tid] = wpre1;
#pragma unroll
            for (int i = 0; i < 3; ++i) {
                if (p_act[i]) {
                    uint4 pk;
                    pk.x = pk2(pfa[i].x, pfb[i].x);
                    pk.y = pk2(pfa[i].y, pfb[i].y);
                    pk.z = pk2(pfa[i].z, pfb[i].z);
                    pk.w = pk2(pfa[i].w, pfb[i].w);
                    *(uint4*)&sPn[p_dst[i]] = pk;
                }
            }
        }
        __syncthreads();
    }

    // epilogue: NHWC bf16 out via swizzled LDS transpose (overlay @0)
#pragma unroll
    for (int ot = 0; ot < 2; ++ot)
#pragma unroll
        for (int pt = 0; pt < 2; ++pt) {
            int px = wv * 64 + pt * 32 + l31;
#pragma unroll
            for (int q2 = 0; q2 < 4; ++q2) {
                int r0 = q2 << 2;
                int unit = ot * 4 + q2;
                int up = unit ^ (px & 7);
                uint2* p = (uint2*)&sT16[px * 64 + up * 8 + half * 4];
                *p = make_uint2(pk2(jb[ot][pt][r0], jb[ot][pt][r0 + 1]),
                                pk2(jb[ot][pt][r0 + 2], jb[ot][pt][r0 + 3]));
            }
        }
    __syncthreads();
#pragma unroll
    for (int k = 0; k < 8; ++k) {
        int col = tid >> 3, u = tid & 7;
        int px = k * 32 + col;
        uint4 v = *(uint4*)&sT16[px * 64 + (u ^ (px & 7)) * 8];
        *(uint4*)(out + zbase + ((size_t)((y0 + k) * 256 + x0 + col)) * 64 + u * 8) = v;
    }
}

// ---------------------------------------------------------------------------
extern "C" void kernel_launch(void* const* d_in, const int* in_sizes, int n_in,
                              void* d_out, int out_size, void* d_ws, size_t ws_size,
                              hipStream_t stream) {
    const float* img  = (const float*)d_in[0];
    const float* gd   = (const float*)d_in[1];
    const float* tw   = (const float*)d_in[2];
    const float* tb   = (const float*)d_in[3];
    const float* ajbf = (const float*)d_in[4];
    const float* kw1  = (const float*)d_in[5];
    const float* kb1  = (const float*)d_in[6];
    const float* kw2  = (const float*)d_in[7];
    const float* kb2  = (const float*)d_in[8];
    const float* kw3  = (const float*)d_in[9];
    const float* kb3  = (const float*)d_in[10];
    const float* kw4  = (const float*)d_in[11];
    const float* kb4  = (const float*)d_in[12];
    const float* kw5  = (const float*)d_in[13];
    const float* kb5  = (const float*)d_in[14];
    const float* akg  = (const float*)d_in[15];
    const float* jw1  = (const float*)d_in[16];
    const float* jb1  = (const float*)d_in[17];
    const float* jw2  = (const float*)d_in[18];
    const float* jb2  = (const float*)d_in[19];
    float* out  = (float*)d_out;

    const size_t TEN = (size_t)2 * HW * 64;      // elements per bf16 tensor
    unsigned short* bufA = (unsigned short*)d_ws;
    unsigned short* imgT = bufA + TEN;
    unsigned short* gdT  = imgT + TEN;           // dead after fuse3 -> reused as bufC
    unsigned short* wT   = gdT + TEN;
    unsigned short* bufC = gdT;

    dim3 gs(16, 32, 2);     // 16x8 tiles -> 1024 blocks (slab-swizzled)
    dim3 gw(8, 32, 2);      // 32x8 tiles -> 512 blocks (slab-swizzled)

    // 1: transpose + weight prep (merged)
    k_pre<<<dim3(1024, 12), 256, 0, stream>>>(img, gd, kw1, kw2, kw3, kw4,
                                              jw1, jw2, kw5, tw, imgT, gdT, wT);

    // 2: fused 1x1 + kg1 + kg2
    k_fuse3<<<gs, 256, 0, stream>>>(imgT, gdT, wT + (size_t)7 * 36864,
                                    wT + (size_t)0 * 36864, wT + (size_t)1 * 36864,
                                    tb, kb1, kb2, ajbf, akg, bufA);

    // 3: fused kg3 + kg4 + jbf combine
    k_jbfm5<<<gw, 256, 0, stream>>>(bufA, img,
                                    wT + (size_t)2 * 36864, wT + (size_t)3 * 36864,
                                    wT + (size_t)6 * 36864,
                                    kb3, kb4, kb5, akg, bufC);

    // 4: jbf conv pair + residual, fp32 NCHW out
    k_conv2x<2><<<gs, 256, 0, stream>>>(bufC, wT + (size_t)4 * 36864, wT + (size_t)5 * 36864,
                                        jb1, jb2, ajbf, img, out);
}